// Round 7
// baseline (572.930 us; speedup 1.0000x reference)
//
#include <hip/hip_runtime.h>
#include <hip/hip_bf16.h>
#include <stdint.h>

typedef __hip_bfloat16 bf16;
typedef __attribute__((ext_vector_type(8))) short short8;
typedef __attribute__((ext_vector_type(4))) float f32x4;

#define SCALE_ 0.08838834764831845f  // 1/sqrt(128)

static __device__ __forceinline__ float bf2f(short u) {
  unsigned int x = ((unsigned int)(unsigned short)u) << 16;
  return __builtin_bit_cast(float, x);
}
static __device__ __forceinline__ short f2bf(float f) {
  __hip_bfloat16 h = __float2bfloat16(f);
  return __builtin_bit_cast(short, h);
}
static __device__ __forceinline__ f32x4 mfma16(short8 a, short8 b, f32x4 c) {
  return __builtin_amdgcn_mfma_f32_16x16x32_bf16(a, b, c, 0, 0, 0);
}
static __device__ __forceinline__ void gl_lds16(const bf16* g, bf16* l) {
  __builtin_amdgcn_global_load_lds(
      (const __attribute__((address_space(1))) unsigned int*)g,
      (__attribute__((address_space(3))) unsigned int*)l, 16, 0, 0);
}

// ---------------------------------------------------------------------------
// GEMM with FUSED f32->bf16 staging conversion.
// C[m][n] = sum_k A[m][k]*Bw[n][k]; A,Bw are f32 row-major; LDS gets bf16.
// 256x256 tile, BK=64, 8 waves (2m x 4n). 8 LDS slots x 16KB (2 K-tiles).
// Unit u (u=0..255): tile u>>2, type u&3 in {A0,B0,A1,B1}, slot u&7,
// KE=(u>>2)*64+((u&2)?32:0). Reg-staged pipeline (T14 + T3/T4):
//   L(u) = phase u-6: issue 4 global_load_dwordx4 (f32) into set u&3
//   W(u) = phase u-2: vmcnt(12) certifies; cvt 16xf2bf; 2x ds_write_b128
//          to the SAME linear addresses gl_lds used (LDS image unchanged)
//   R(u) = phase u (A also u+1; B at u-1): after barrier.
// Every phase: vmcnt(12) (4 units x 4 loads in flight, uniform);
// barrier only at p0/p2. Write->read visibility: writer's per-phase
// lgkmcnt(0) + the next p0/p2 barrier. WAR on slot reuse: >=2 barriers
// between last read of evicted unit and the overwrite. Load->use slack =
// 4 phases (~4000cy >> 900cy HBM). Sets rgs0..3 statically indexed (rule 20);
// sched_barrier(0) after every counted wait (rule 18).
// Read path, swizzle, MFMA schedule, epilogue: identical to round-5/6.
// Rows >= M1 come from A2 (prompt f32, clamped); outputs >= M1 go to Cp.
// CF != null -> f32 output (out-projection).
// ---------------------------------------------------------------------------
__global__ __launch_bounds__(512, 2) void gemm_bt(
    const float* __restrict__ A, const float* __restrict__ A2,
    const float* __restrict__ B0, const float* __restrict__ B1, const float* __restrict__ B2w,
    bf16* __restrict__ C0, bf16* __restrict__ C1, bf16* __restrict__ C2,
    bf16* __restrict__ P1, bf16* __restrict__ P2,
    float* __restrict__ CF,
    int M1, int Mtot)
{
  __shared__ char lds[131072];   // 8 slots x 16KB
  const int tid = threadIdx.x, w = tid >> 6, l = tid & 63;
  const int lr = l & 15, lg = l >> 4;
  const int wm = w >> 2, wn = w & 3;
  const int z = blockIdx.z;
  const float* Bw = (z == 0) ? B0 : ((z == 1) ? B1 : B2w);
  bf16* C  = (z == 0) ? C0 : ((z == 1) ? C1 : C2);
  bf16* Cp = (z == 0) ? (bf16*)0 : ((z == 1) ? P1 : P2);

  // T1: bijective chunked XCD swizzle (gridDim.x % 8 == 0), n fastest.
  const int cpx = gridDim.x >> 3, orig = blockIdx.x;
  const int wg = (orig & 7) * cpx + (orig >> 3);
  const long m0 = (long)(wg >> 4) * 256;
  const long n0 = (long)(wg & 15) * 256;

  // staging source mapping (same element mapping as rounds 5/6, f32 now):
  // thread -> row r0 (and r0+128), col chunk c0 (8 elems)
  const int r0 = ((tid >> 3) << 1) | ((tid >> 2) & 1);
  const int c0 = (tid & 3) ^ ((tid >> 3) & 3);
  const float *pA0, *pA1;
  {
    long mx = (long)(Mtot - M1) - 1;
    long g0 = m0 + r0, g1 = m0 + r0 + 128;
    const float *q0, *q1;
    if (g0 < M1) q0 = A + g0 * 4096;
    else { long rr = g0 - M1; if (rr > mx) rr = mx; q0 = A2 + rr * 4096; }
    if (g1 < M1) q1 = A + g1 * 4096;
    else { long rr = g1 - M1; if (rr > mx) rr = mx; q1 = A2 + rr * 4096; }
    pA0 = q0 + c0 * 8;
    pA1 = q1 + c0 * 8;
  }
  const float* pB0 = Bw + (n0 + r0) * 4096 + c0 * 8;
  const float* pB1 = pB0 + (long)128 * 4096;

  // fragment-read offsets (unchanged, verified)
  const int ro  = (lr >> 1) * 128 + (((lr & 1) * 4) + (lg ^ ((lr >> 1) & 3))) * 16;
  const int aro = wm * 8192 + ro;   // + mi*1024 within A unit
  const int bro = wn * 4096 + ro;   // + ni*1024 within B unit

  f32x4 acc[8][4];
#pragma unroll
  for (int i = 0; i < 8; i++)
#pragma unroll
    for (int j = 0; j < 4; j++) acc[i][j] = (f32x4){0.f, 0.f, 0.f, 0.f};

  short8 af[4], bf[4];
  f32x4 rgs0[4], rgs1[4], rgs2[4], rgs3[4];   // 4 in-flight unit sets

#define LOADU(RG_, ISA_, KE_)                                                \
  {                                                                          \
    const float* pl0_ = ((ISA_) ? pA0 : pB0) + (KE_);                        \
    const float* pl1_ = ((ISA_) ? pA1 : pB1) + (KE_);                        \
    RG_[0] = *(const f32x4*)pl0_;                                            \
    RG_[1] = *(const f32x4*)(pl0_ + 4);                                      \
    RG_[2] = *(const f32x4*)pl1_;                                            \
    RG_[3] = *(const f32x4*)(pl1_ + 4);                                      \
  }
#define WRITEU(RG_, SLB_)                                                    \
  {                                                                          \
    bf16* dw_ = (bf16*)(lds + (SLB_)) + tid * 8;                             \
    short8 w0_, w1_;                                                         \
    _Pragma("unroll") for (int q_ = 0; q_ < 4; q_++) {                       \
      w0_[q_]     = f2bf(RG_[0][q_]); w0_[4 + q_] = f2bf(RG_[1][q_]);        \
      w1_[q_]     = f2bf(RG_[2][q_]); w1_[4 + q_] = f2bf(RG_[3][q_]);        \
    }                                                                        \
    *(short8*)dw_ = w0_;                                                     \
    *(short8*)(dw_ + 4096) = w1_;                                            \
  }
#define VMW(VMS_)                                                            \
  asm volatile("s_waitcnt vmcnt(" VMS_ ")" ::: "memory");
#define PHASE(VMS_, BAR_, PRB_, AU_, BU_, MO_, LB_, WC_, LC_)                \
  {                                                                          \
    VMW(VMS_)                                                                \
    BAR_                                                                     \
    __builtin_amdgcn_sched_barrier(0);                                       \
    WC_                                                                      \
    LC_                                                                      \
    const char* ab_ = lds + (PRB_) + (AU_) + aro;                            \
    _Pragma("unroll") for (int mi = 0; mi < 4; mi++)                         \
      af[mi] = *(const short8*)(ab_ + ((MO_) + mi) * 1024);                  \
    if (LB_) {                                                               \
      const char* bb_ = lds + (PRB_) + (BU_) + bro;                          \
      _Pragma("unroll") for (int ni = 0; ni < 4; ni++)                       \
        bf[ni] = *(const short8*)(bb_ + ni * 1024);                          \
    }                                                                        \
    asm volatile("s_waitcnt lgkmcnt(0)" ::: "memory");                       \
    __builtin_amdgcn_sched_barrier(0);                                       \
    __builtin_amdgcn_s_setprio(1);                                           \
    _Pragma("unroll") for (int mi = 0; mi < 4; mi++)                         \
      _Pragma("unroll") for (int ni = 0; ni < 4; ni++)                       \
        acc[(MO_) + mi][ni] = mfma16(af[mi], bf[ni], acc[(MO_) + mi][ni]);   \
    __builtin_amdgcn_s_setprio(0);                                           \
  }
#define BARR __builtin_amdgcn_s_barrier();

  // ---- prologue: units 0..5 ----
  LOADU(rgs0, 1, 0)    // u0 A0 t0
  LOADU(rgs1, 0, 0)    // u1 B0 t0
  LOADU(rgs2, 1, 32)   // u2 A1 t0
  LOADU(rgs3, 0, 32)   // u3 B1 t0
  VMW("12") __builtin_amdgcn_sched_barrier(0);
  WRITEU(rgs0, 0)          // u0 -> slot0
  LOADU(rgs0, 1, 64)       // u4 A0 t1
  VMW("12") __builtin_amdgcn_sched_barrier(0);
  WRITEU(rgs1, 16384)      // u1 -> slot1
  LOADU(rgs1, 0, 64)       // u5 B0 t1
  asm volatile("s_waitcnt lgkmcnt(0)" ::: "memory");
  __builtin_amdgcn_sched_barrier(0);

  // ---- main loop: tiles 0..61 ----
  for (int t = 0; t < 62; ++t) {
    const int pt = (t & 1) * 65536;
    const int qt = 65536 - pt;
    const int keN = (t + 1) * 64 + 32;   // A1/B1 of tile t+1
    const int keF = (t + 2) * 64;        // A0/B0 of tile t+2
    PHASE("12", BARR, pt, 0,     16384, 0, 1, WRITEU(rgs2, pt + 32768), LOADU(rgs2, 1, keN))
    PHASE("12",     , pt, 0,     16384, 4, 0, WRITEU(rgs3, pt + 49152), LOADU(rgs3, 0, keN))
    PHASE("12", BARR, pt, 32768, 49152, 0, 1, WRITEU(rgs0, qt),         LOADU(rgs0, 1, keF))
    PHASE("12",     , pt, 32768, 49152, 4, 0, WRITEU(rgs1, qt + 16384), LOADU(rgs1, 0, keF))
  }
  // ---- tile 62 (parity 0): last loads (A1/B1 of 63, KE=4064) ----
  PHASE("12", BARR, 0, 0,     16384, 0, 1, WRITEU(rgs2, 32768), LOADU(rgs2, 1, 4064))
  PHASE("12",     , 0, 0,     16384, 4, 0, WRITEU(rgs3, 49152), LOADU(rgs3, 0, 4064))
  PHASE("12", BARR, 0, 32768, 49152, 0, 1, WRITEU(rgs0, 65536), )
  PHASE("8",      , 0, 32768, 49152, 4, 0, WRITEU(rgs1, 65536 + 16384), )
  // ---- tile 63 (parity 1): drain ----
  PHASE("4",  BARR, 65536, 0,     16384, 0, 1, WRITEU(rgs2, 65536 + 32768), )
  PHASE("0",      , 65536, 0,     16384, 4, 0, WRITEU(rgs3, 65536 + 49152), )
  PHASE("0",  BARR, 65536, 32768, 49152, 0, 1, , )
  PHASE("0",      , 65536, 32768, 49152, 4, 0, , )

#undef BARR
#undef PHASE
#undef VMW
#undef WRITEU
#undef LOADU

  // epilogue: C/D layout col=lane&15, row=(lane>>4)*4+j
#pragma unroll
  for (int mi = 0; mi < 8; mi++) {
#pragma unroll
    for (int ni = 0; ni < 4; ni++) {
      long col = n0 + wn * 64 + ni * 16 + lr;
      f32x4 v = acc[mi][ni];
#pragma unroll
      for (int j = 0; j < 4; j++) {
        long row = m0 + wm * 128 + mi * 16 + lg * 4 + j;
        if (CF) {
          CF[row * 4096 + col] = v[j];
        } else if (row < M1) {
          *(short*)(C + row * 4096 + col) = f2bf(v[j]);
        } else if (Cp != 0 && row < Mtot) {
          *(short*)(Cp + (row - M1) * 4096 + col) = f2bf(v[j]);
        }
      }
    }
  }
}

// ---------------------------------------------------------------------------
// RoPE in-place on q / k  ([2048][4096]), freqs f32.
// ---------------------------------------------------------------------------
__global__ __launch_bounds__(256) void rope_qk(
    bf16* __restrict__ Q, bf16* __restrict__ Kb,
    const float* __restrict__ FC, const float* __restrict__ FS)
{
  const int row = blockIdx.x;
  const int s = row & 1023;
  const int t = threadIdx.x;
  bf16* base = (blockIdx.y ? Kb : Q) + (long)row * 4096 + t * 16;
  short8 v0 = *(const short8*)base;
  short8 v1 = *(const short8*)(base + 8);
  const float* cp = FC + s * 64 + (t & 7) * 8;
  const float* sp = FS + s * 64 + (t & 7) * 8;
  f32x4 c0 = *(const f32x4*)cp;
  f32x4 c1 = *(const f32x4*)(cp + 4);
  f32x4 s0 = *(const f32x4*)sp;
  f32x4 s1 = *(const f32x4*)(sp + 4);
  short8 o0, o1;
#pragma unroll
  for (int j = 0; j < 4; j++) {
    float c = c0[j], sn = s0[j];
    float e = bf2f(v0[2 * j]), od = bf2f(v0[2 * j + 1]);
    o0[2 * j] = f2bf(e * c - od * sn);
    o0[2 * j + 1] = f2bf(e * sn + od * c);
    float c2 = c1[j], sn2 = s1[j];
    float e2 = bf2f(v1[2 * j]), od2 = bf2f(v1[2 * j + 1]);
    o1[2 * j] = f2bf(e2 * c2 - od2 * sn2);
    o1[2 * j + 1] = f2bf(e2 * sn2 + od2 * c2);
  }
  *(short8*)base = o0;
  *(short8*)(base + 8) = o1;
}

// ---------------------------------------------------------------------------
// V transpose: v[b][s][h][d] -> vT[bh][d][s]
// ---------------------------------------------------------------------------
__global__ __launch_bounds__(256) void transpose_v(
    const bf16* __restrict__ V, bf16* __restrict__ VT)
{
  __shared__ bf16 T[64 * 128];
  const int tid = threadIdx.x;
  const int st = blockIdx.x * 64, bh = blockIdx.y;
  const int b = bh >> 5, h = bh & 31;
  const bf16* src = V + ((long)(b * 1024 + st)) * 4096 + h * 128;
#pragma unroll
  for (int rr = 0; rr < 4; ++rr) {
    int i = tid + rr * 256;
    int s_l = i >> 4, c = i & 15;
    short8 v = *(const short8*)(src + (long)s_l * 4096 + c * 8);
    *(short8*)((char*)T + s_l * 256 + ((c ^ (s_l & 7)) * 16)) = v;
  }
  __syncthreads();
#pragma unroll
  for (int rr = 0; rr < 4; ++rr) {
    int i = tid + rr * 256;
    int d = i >> 3, cs = i & 7;
    short8 ov;
#pragma unroll
    for (int e = 0; e < 8; e++) {
      int s_l = cs * 8 + e;
      ov[e] = *(const short*)((char*)T + s_l * 256 + (((d >> 3) ^ (s_l & 7)) * 16) + (d & 7) * 2);
    }
    *(short8*)(VT + ((long)bh * 128 + d) * 1024 + st + cs * 8) = ov;
  }
}

// ---------------------------------------------------------------------------
// Flash attention, causal, + fused gated prompt attention.
// Output now f32 (feeds the f32 A-path of the out-projection GEMM).
// ---------------------------------------------------------------------------
__global__ __launch_bounds__(256) void flash_attn(
    const bf16* __restrict__ Q, const bf16* __restrict__ Kg, const bf16* __restrict__ VT,
    const bf16* __restrict__ PK, const bf16* __restrict__ PV,
    const float* __restrict__ GATE, float* __restrict__ O)
{
  __shared__ bf16 Kl[32 * 128];
  __shared__ bf16 Vl[128 * 32];
  __shared__ bf16 PKl[16 * 128];
  __shared__ bf16 PVl[128 * 16];
  __shared__ bf16 Pl[4][16 * 32];
  const int tid = threadIdx.x, w = tid >> 6, l = tid & 63;
  const int lg = l >> 4, lr = l & 15;
  const int qb = blockIdx.x, bh = blockIdx.y;
  const int b = bh >> 5, h = bh & 31;
  const int q0 = qb * 64 + w * 16;

  short8 qf[4];
  {
    const bf16* qp = Q + ((long)(b * 1024 + q0 + lr)) * 4096 + h * 128 + lg * 8;
#pragma unroll
    for (int c = 0; c < 4; c++) qf[c] = *(const short8*)(qp + c * 32);
  }
  {
    int rowp = tid >> 4, pc = tid & 15, lc = pc ^ (rowp & 7);
    short8 v = {0, 0, 0, 0, 0, 0, 0, 0};
    if (rowp < 10) v = *(const short8*)(PK + (long)rowp * 4096 + h * 128 + lc * 8);
    *(short8*)((char*)PKl + tid * 16) = v;
  }
  {
    int d = tid >> 1, pb = (tid & 1) * 8;
#pragma unroll
    for (int e = 0; e < 8; e++) {
      int p = pb + e;
      short v = 0;
      if (p < 10) v = __builtin_bit_cast(short, PV[(long)p * 4096 + h * 128 + d]);
      *(short*)((char*)PVl + d * 32 + (((p >> 3) ^ (d & 1)) * 16) + (p & 7) * 2) = v;
    }
  }
  const float gate = GATE[h];

  f32x4 o[8];
#pragma unroll
  for (int i = 0; i < 8; i++) o[i] = (f32x4){0.f, 0.f, 0.f, 0.f};
  float m_[4] = {-1e30f, -1e30f, -1e30f, -1e30f};
  float l_[4] = {0.f, 0.f, 0.f, 0.f};

  const int nt = (qb + 1) * 2;
  const bf16* Kbase = Kg + ((long)b * 1024) * 4096 + h * 128;
  const bf16* Vbase = VT + ((long)bh) * 128 * 1024;
  const int cb1 = w * 64, cb2 = 256 + w * 64;
  const int iA = cb1 + l, iB = cb2 + l;
  bf16* pw = &Pl[w][0];

  for (int j = 0; j < nt; ++j) {
    __syncthreads();
    {
      const bf16* gA = Kbase + (long)(j * 32 + (iA >> 4)) * 4096 + ((iA & 15) ^ ((iA >> 4) & 7)) * 8;
      const bf16* gB = Kbase + (long)(j * 32 + (iB >> 4)) * 4096 + ((iB & 15) ^ ((iB >> 4) & 7)) * 8;
      gl_lds16(gA, Kl + cb1 * 8);
      gl_lds16(gB, Kl + cb2 * 8);
      const bf16* vA = Vbase + (long)(iA >> 2) * 1024 + j * 32 + ((iA & 3) ^ ((iA >> 2) & 3)) * 8;
      const bf16* vB = Vbase + (long)(iB >> 2) * 1024 + j * 32 + ((iB & 3) ^ ((iB >> 2) & 3)) * 8;
      gl_lds16(vA, Vl + cb1 * 8);
      gl_lds16(vB, Vl + cb2 * 8);
    }
    __syncthreads();

    f32x4 s[2];
#pragma unroll
    for (int ns = 0; ns < 2; ns++) {
      f32x4 a = (f32x4){0.f, 0.f, 0.f, 0.f};
      int krow = ns * 16 + lr;
      const char* kp = (const char*)Kl + krow * 256;
      int sw = krow & 7;
#pragma unroll
      for (int c = 0; c < 4; c++) {
        short8 kf = *(const short8*)(kp + (((c * 4 + lg) ^ sw) * 16));
        a = mfma16(qf[c], kf, a);
      }
      int key = j * 32 + krow;
#pragma unroll
      for (int r = 0; r < 4; r++) {
        int qr = q0 + lg * 4 + r;
        s[ns][r] = a[r] * SCALE_ + ((key <= qr) ? 0.0f : -1e30f);
      }
    }
    float mx[4], cor[4], sum[4];
#pragma unroll
    for (int r = 0; r < 4; r++) mx[r] = fmaxf(s[0][r], s[1][r]);
#pragma unroll
    for (int xm = 1; xm < 16; xm <<= 1)
#pragma unroll
      for (int r = 0; r < 4; r++) mx[r] = fmaxf(mx[r], __shfl_xor(mx[r], xm, 64));
#pragma unroll
    for (int r = 0; r < 4; r++) {
      float mn = fmaxf(m_[r], mx[r]);
      cor[r] = __expf(m_[r] - mn);
      m_[r] = mn;
      s[0][r] = __expf(s[0][r] - mn);
      s[1][r] = __expf(s[1][r] - mn);
      sum[r] = s[0][r] + s[1][r];
    }
#pragma unroll
    for (int xm = 1; xm < 16; xm <<= 1)
#pragma unroll
      for (int r = 0; r < 4; r++) sum[r] += __shfl_xor(sum[r], xm, 64);
#pragma unroll
    for (int r = 0; r < 4; r++) l_[r] = l_[r] * cor[r] + sum[r];
#pragma unroll
    for (int df = 0; df < 8; df++)
#pragma unroll
      for (int r = 0; r < 4; r++) o[df][r] *= cor[r];

#pragma unroll
    for (int ns = 0; ns < 2; ns++)
#pragma unroll
      for (int r = 0; r < 4; r++)
        *(short*)((char*)pw + ((lg * 4 + r) * 32 + ns * 16 + lr) * 2) = f2bf(s[ns][r]);
    asm volatile("s_waitcnt lgkmcnt(0)" ::: "memory");
    __builtin_amdgcn_sched_barrier(0);
    short8 pf = *(const short8*)(pw + lr * 32 + lg * 8);

#pragma unroll
    for (int df = 0; df < 8; df++) {
      int d = df * 16 + lr;
      short8 vf = *(const short8*)((const char*)Vl + d * 64 + ((lg ^ (d & 3)) * 16));
      o[df] = mfma16(pf, vf, o[df]);
    }
  }

  // ---- prompt attention ----
  f32x4 ps;
  {
    f32x4 a = (f32x4){0.f, 0.f, 0.f, 0.f};
    const char* kp = (const char*)PKl + lr * 256;
    int sw = lr & 7;
#pragma unroll
    for (int c = 0; c < 4; c++) {
      short8 kf = *(const short8*)(kp + (((c * 4 + lg) ^ sw) * 16));
      a = mfma16(qf[c], kf, a);
    }
#pragma unroll
    for (int r = 0; r < 4; r++) ps[r] = (lr < 10) ? a[r] * SCALE_ : -1e30f;
  }
  {
    float pm[4], pss[4];
#pragma unroll
    for (int r = 0; r < 4; r++) pm[r] = ps[r];
#pragma unroll
    for (int xm = 1; xm < 16; xm <<= 1)
#pragma unroll
      for (int r = 0; r < 4; r++) pm[r] = fmaxf(pm[r], __shfl_xor(pm[r], xm, 64));
#pragma unroll
    for (int r = 0; r < 4; r++) { ps[r] = __expf(ps[r] - pm[r]); pss[r] = ps[r]; }
#pragma unroll
    for (int xm = 1; xm < 16; xm <<= 1)
#pragma unroll
      for (int r = 0; r < 4; r++) pss[r] += __shfl_xor(pss[r], xm, 64);
#pragma unroll
    for (int r = 0; r < 4; r++) ps[r] = ps[r] / pss[r];
  }
#pragma unroll
  for (int r = 0; r < 4; r++) {
    *(short*)((char*)pw + ((lg * 4 + r) * 32 + lr) * 2) = f2bf(ps[r]);
    *(short*)((char*)pw + ((lg * 4 + r) * 32 + 16 + lr) * 2) = 0;
  }
  asm volatile("s_waitcnt lgkmcnt(0)" ::: "memory");
  __builtin_amdgcn_sched_barrier(0);
  short8 pf2 = *(const short8*)(pw + lr * 32 + lg * 8);
  f32x4 po[8];
#pragma unroll
  for (int df = 0; df < 8; df++) {
    int d = df * 16 + lr;
    short8 vf = {0, 0, 0, 0, 0, 0, 0, 0};
    if (lg < 2) vf = *(const short8*)((const char*)PVl + d * 32 + ((lg ^ (d & 1)) * 16));
    po[df] = mfma16(pf2, vf, (f32x4){0.f, 0.f, 0.f, 0.f});
  }

  float* op = O + ((long)(b * 1024 + q0 + lg * 4)) * 4096 + h * 128 + lr;
#pragma unroll
  for (int df = 0; df < 8; df++)
#pragma unroll
    for (int r = 0; r < 4; r++) {
      op[(long)r * 4096 + df * 16] = o[df][r] / l_[r] + gate * po[df][r];
    }
}

// ---------------------------------------------------------------------------
extern "C" void kernel_launch(void* const* d_in, const int* in_sizes, int n_in,
                              void* d_out, int out_size, void* d_ws, size_t ws_size,
                              hipStream_t stream) {
  (void)in_sizes; (void)n_in; (void)out_size; (void)ws_size;
  const float* x      = (const float*)d_in[0];
  const float* wq     = (const float*)d_in[1];
  const float* wk     = (const float*)d_in[2];
  const float* wv     = (const float*)d_in[3];
  const float* wo     = (const float*)d_in[4];
  const float* prompt = (const float*)d_in[5];
  const float* gate   = (const float*)d_in[6];
  const float* fcos   = (const float*)d_in[7];
  const float* fsin   = (const float*)d_in[8];
  float* out = (float*)d_out;
  char* ws = (char*)d_ws;

  size_t o = 0;
  bf16* q_ws  = (bf16*)(ws + o); o += (size_t)2048 * 4096 * 2;
  bf16* k_ws  = (bf16*)(ws + o); o += (size_t)2048 * 4096 * 2;
  bf16* v_ws  = (bf16*)(ws + o); o += (size_t)2048 * 4096 * 2;
  bf16* vT_ws = (bf16*)(ws + o); o += (size_t)2048 * 4096 * 2;
  bf16* pk_ws = (bf16*)(ws + o); o += (size_t)40960 * 2;
  bf16* pv_ws = (bf16*)(ws + o); o += (size_t)40960 * 2;
  float* attnF = (float*)(ws + ((o + 255) & ~(size_t)255));

  // 1. QKV (+prompt K/V rows), f32 inputs, fused cvt in staging
  gemm_bt<<<dim3(144, 1, 3), 512, 0, stream>>>(
      x, prompt, wq, wk, wv, q_ws, k_ws, v_ws, pk_ws, pv_ws, (float*)0, 2048, 2058);
  // 2. RoPE on q, k
  rope_qk<<<dim3(2048, 2), 256, 0, stream>>>(q_ws, k_ws, fcos, fsin);
  // 3. V -> VT
  transpose_v<<<dim3(16, 64), 256, 0, stream>>>(v_ws, vT_ws);
  // 4. flash attention + gated prompt attention (f32 out)
  flash_attn<<<dim3(16, 64), 256, 0, stream>>>(
      q_ws, k_ws, vT_ws, pk_ws, pv_ws, gate, attnF);
  // 5. output projection: A = attnF (f32), B = wo (f32), f32 out
  gemm_bt<<<dim3(128, 1, 1), 512, 0, stream>>>(
      attnF, attnF, wo, wo, wo, q_ws, q_ws, q_ws,
      (bf16*)0, (bf16*)0, out, 2048, 2048);
}

// Round 8
// 524.936 us; speedup vs baseline: 1.0914x; 1.0914x over previous
//
#include <hip/hip_runtime.h>
#include <hip/hip_bf16.h>
#include <stdint.h>

typedef __hip_bfloat16 bf16;
typedef __attribute__((ext_vector_type(8))) short short8;
typedef __attribute__((ext_vector_type(4))) float f32x4;

#define SCALE_ 0.08838834764831845f  // 1/sqrt(128)

static __device__ __forceinline__ float bf2f(short u) {
  unsigned int x = ((unsigned int)(unsigned short)u) << 16;
  return __builtin_bit_cast(float, x);
}
static __device__ __forceinline__ short f2bf(float f) {
  __hip_bfloat16 h = __float2bfloat16(f);
  return __builtin_bit_cast(short, h);
}
static __device__ __forceinline__ f32x4 mfma16(short8 a, short8 b, f32x4 c) {
  return __builtin_amdgcn_mfma_f32_16x16x32_bf16(a, b, c, 0, 0, 0);
}
static __device__ __forceinline__ void gl_lds16(const bf16* g, bf16* l) {
  __builtin_amdgcn_global_load_lds(
      (const __attribute__((address_space(1))) unsigned int*)g,
      (__attribute__((address_space(3))) unsigned int*)l, 16, 0, 0);
}

// ---------------------------------------------------------------------------
// f32 -> bf16 conversion for x, wq, wk, wv, wo, prompt (one fused launch).
// ---------------------------------------------------------------------------
__global__ __launch_bounds__(256) void cvt6(
    const float* __restrict__ sx, const float* __restrict__ sq,
    const float* __restrict__ sk, const float* __restrict__ sv,
    const float* __restrict__ so, const float* __restrict__ sp,
    bf16* __restrict__ dx, bf16* __restrict__ dq, bf16* __restrict__ dk,
    bf16* __restrict__ dv, bf16* __restrict__ d4, bf16* __restrict__ dp)
{
  int b = blockIdx.x;
  const float* s; bf16* d; int off;
  if (b < 4096)       { s = sx; d = dx; off = b; }
  else if (b < 12288) { s = sq; d = dq; off = b - 4096; }
  else if (b < 20480) { s = sk; d = dk; off = b - 12288; }
  else if (b < 28672) { s = sv; d = dv; off = b - 20480; }
  else if (b < 36864) { s = so; d = d4; off = b - 28672; }
  else                { s = sp; d = dp; off = b - 36864; }
  long base = (long)off * 2048 + threadIdx.x * 8;
  f32x4 a = *(const f32x4*)(s + base);
  f32x4 c = *(const f32x4*)(s + base + 4);
  short8 o;
#pragma unroll
  for (int j = 0; j < 4; j++) { o[j] = f2bf(a[j]); o[4 + j] = f2bf(c[j]); }
  *(short8*)(d + base) = o;
}

// ---------------------------------------------------------------------------
// GEMM (round-6 verified structure, now templated):
// C[m][n] = sum_k A[m][k]*Bw[n][k], bf16 in, 256x256 tile, BK=64, 8 waves.
// NKT = number of 64-elem K-tiles. KSPLIT: blockIdx.z selects a K-half,
// output goes to CF + z*M*4096 (f32 partials; combined by addf).
// 8-phase DEPTH-6 schedule, vmcnt(8) at p0/p2 only (T3+T4), setprio (T5),
// XOR-swizzled LDS staged via gl_lds with inverse perm on global src (T2,
// rule 21), bijective XCD swizzle (T1). See round-5/6 derivation.
// ---------------------------------------------------------------------------
template <int NKT, bool KSPLIT>
__global__ __launch_bounds__(512, 2) void gemm_bt(
    const bf16* __restrict__ A, const bf16* __restrict__ A2,
    const bf16* __restrict__ B0, const bf16* __restrict__ B1, const bf16* __restrict__ B2w,
    bf16* __restrict__ C0, bf16* __restrict__ C1, bf16* __restrict__ C2,
    bf16* __restrict__ P1, bf16* __restrict__ P2,
    float* __restrict__ CF,
    int M1, int Mtot)
{
  __shared__ char lds[131072];   // 8 slots x 16KB
  const int tid = threadIdx.x, w = tid >> 6, l = tid & 63;
  const int lr = l & 15, lg = l >> 4;
  const int wm = w >> 2, wn = w & 3;
  const int z = blockIdx.z;
  const bf16* Bw = KSPLIT ? B0 : ((z == 0) ? B0 : ((z == 1) ? B1 : B2w));
  bf16* C  = (z == 0) ? C0 : ((z == 1) ? C1 : C2);
  bf16* Cp = (KSPLIT || z == 0) ? (bf16*)0 : ((z == 1) ? P1 : P2);
  float* CFz = CF;
  long koff = 0;
  if (KSPLIT) { koff = (long)z * NKT * 64; CFz = CF + (long)z * M1 * 4096; }

  // T1: bijective chunked XCD swizzle (gridDim.x % 8 == 0), n fastest.
  const int cpx = gridDim.x >> 3, orig = blockIdx.x;
  const int wg = (orig & 7) * cpx + (orig >> 3);
  const long m0 = (long)(wg >> 4) * 256;
  const long n0 = (long)(wg & 15) * 256;

  // staging source mapping: thread -> rows r0, r0+128; col chunk c0
  const int r0 = ((tid >> 3) << 1) | ((tid >> 2) & 1);
  const int c0 = (tid & 3) ^ ((tid >> 3) & 3);
  const bf16 *pa0, *pa1;
  {
    long mx = (long)(Mtot - M1) - 1;
    long g0 = m0 + r0, g1 = m0 + r0 + 128;
    const bf16 *q0, *q1;
    if (g0 < M1) q0 = A + g0 * 4096;
    else { long rr = g0 - M1; if (rr > mx) rr = mx; q0 = A2 + rr * 4096; }
    if (g1 < M1) q1 = A + g1 * 4096;
    else { long rr = g1 - M1; if (rr > mx) rr = mx; q1 = A2 + rr * 4096; }
    pa0 = q0 + c0 * 8 + koff;
    pa1 = q1 + c0 * 8 + koff;
  }
  const bf16* pb0 = Bw + (n0 + r0) * 4096 + c0 * 8 + koff;
  const bf16* pb1 = pb0 + (long)128 * 4096;

  // fragment-read offsets (swizzled; inverse of staging map)
  const int ro  = (lr >> 1) * 128 + (((lr & 1) * 4) + (lg ^ ((lr >> 1) & 3))) * 16;
  const int aro = wm * 8192 + ro;   // + mi*1024 within A unit
  const int bro = wn * 4096 + ro;   // + ni*1024 within B unit

  f32x4 acc[8][4];
#pragma unroll
  for (int i = 0; i < 8; i++)
#pragma unroll
    for (int j = 0; j < 4; j++) acc[i][j] = (f32x4){0.f, 0.f, 0.f, 0.f};

  short8 af[4], bf[4];

#define STGA(S_, KE_)                                                        \
  {                                                                          \
    bf16* d_ = (bf16*)(lds + (S_) * 16384) + tid * 8;                        \
    gl_lds16(pa0 + (KE_), d_);                                               \
    gl_lds16(pa1 + (KE_), d_ + 4096);                                        \
  }
#define STGB(S_, KE_)                                                        \
  {                                                                          \
    bf16* d_ = (bf16*)(lds + (S_) * 16384) + tid * 8;                        \
    gl_lds16(pb0 + (KE_), d_);                                               \
    gl_lds16(pb1 + (KE_), d_ + 4096);                                        \
  }
#define SYNC(VM_)                                                            \
  {                                                                          \
    asm volatile("s_waitcnt vmcnt(" VM_ ")" ::: "memory");                   \
    __builtin_amdgcn_s_barrier();                                            \
    __builtin_amdgcn_sched_barrier(0);                                       \
  }
#define PHASE(PRB_, AU_, BU_, MO_, LB_, STG_)                                \
  {                                                                          \
    STG_                                                                     \
    const char* ab_ = lds + (PRB_) + (AU_) + aro;                            \
    _Pragma("unroll") for (int mi = 0; mi < 4; mi++)                         \
      af[mi] = *(const short8*)(ab_ + ((MO_) + mi) * 1024);                  \
    if (LB_) {                                                               \
      const char* bb_ = lds + (PRB_) + (BU_) + bro;                          \
      _Pragma("unroll") for (int ni = 0; ni < 4; ni++)                       \
        bf[ni] = *(const short8*)(bb_ + ni * 1024);                          \
    }                                                                        \
    asm volatile("s_waitcnt lgkmcnt(0)" ::: "memory");                       \
    __builtin_amdgcn_sched_barrier(0);                                       \
    __builtin_amdgcn_s_setprio(1);                                           \
    _Pragma("unroll") for (int mi = 0; mi < 4; mi++)                         \
      _Pragma("unroll") for (int ni = 0; ni < 4; ni++)                       \
        acc[(MO_) + mi][ni] = mfma16(af[mi], bf[ni], acc[(MO_) + mi][ni]);   \
    __builtin_amdgcn_s_setprio(0);                                           \
  }
#define KT(PRB_, S6_, S7_, S8_, S9_, KE1_, KE2_)                             \
  SYNC("8") PHASE(PRB_, 0, 16384, 0, 1, STGA(S6_, KE1_))                     \
  PHASE(PRB_, 0, 16384, 4, 0, STGB(S7_, KE1_))                               \
  SYNC("8") PHASE(PRB_, 32768, 49152, 0, 1, STGA(S8_, KE2_))                 \
  PHASE(PRB_, 32768, 49152, 4, 0, STGB(S9_, KE2_))

  // prologue: units 0..5
  STGA(0, 0) STGB(1, 0) STGA(2, 32) STGB(3, 32) STGA(4, 64) STGB(5, 64)

  // tiles 0..NKT-3 (full staging)
  for (int t = 0; t < NKT - 2; t += 2) {
    const int ka = (t + 1) * 64 + 32, kb = (t + 2) * 64;
    const int kc = (t + 2) * 64 + 32, kd = (t + 3) * 64;
    KT(0, 6, 7, 0, 1, ka, kb)        // tile t   (even, parity 0)
    KT(65536, 2, 3, 4, 5, kc, kd)    // tile t+1 (odd,  parity 1)
  }
  // tile NKT-2 (parity 0): stage only A1/B1 of last tile
  {
    const int kel = (NKT - 1) * 64 + 32;
    SYNC("8") PHASE(0, 0, 16384, 0, 1, STGA(6, kel))
    PHASE(0, 0, 16384, 4, 0, STGB(7, kel))
    SYNC("8") PHASE(0, 32768, 49152, 0, 1, )
    PHASE(0, 32768, 49152, 4, 0, )
  }
  // tile NKT-1 (parity 1): drain
  SYNC("4") PHASE(65536, 0, 16384, 0, 1, )
  PHASE(65536, 0, 16384, 4, 0, )
  SYNC("0") PHASE(65536, 32768, 49152, 0, 1, )
  PHASE(65536, 32768, 49152, 4, 0, )

#undef KT
#undef PHASE
#undef SYNC
#undef STGB
#undef STGA

  // epilogue: C/D layout col=lane&15, row=(lane>>4)*4+j
#pragma unroll
  for (int mi = 0; mi < 8; mi++) {
#pragma unroll
    for (int ni = 0; ni < 4; ni++) {
      long col = n0 + wn * 64 + ni * 16 + lr;
      f32x4 v = acc[mi][ni];
#pragma unroll
      for (int j = 0; j < 4; j++) {
        long row = m0 + wm * 128 + mi * 16 + lg * 4 + j;
        if (CFz) {
          CFz[row * 4096 + col] = v[j];
        } else if (row < M1) {
          *(short*)(C + row * 4096 + col) = f2bf(v[j]);
        } else if (Cp != 0 && row < Mtot) {
          *(short*)(Cp + (row - M1) * 4096 + col) = f2bf(v[j]);
        }
      }
    }
  }
}

// ---------------------------------------------------------------------------
// addf: out = p0 + p1  (K-split partial combine), 8.39M f32, f32x4 loads.
// ---------------------------------------------------------------------------
__global__ __launch_bounds__(256) void addf(
    const float* __restrict__ p0, const float* __restrict__ p1,
    float* __restrict__ out)
{
  long i = ((long)blockIdx.x * 256 + threadIdx.x) * 4;
  f32x4 a = *(const f32x4*)(p0 + i);
  f32x4 b = *(const f32x4*)(p1 + i);
#pragma unroll
  for (int j = 0; j < 4; j++) a[j] += b[j];
  *(f32x4*)(out + i) = a;
}

// ---------------------------------------------------------------------------
// RoPE in-place on q / k  ([2048][4096]), freqs f32.
// ---------------------------------------------------------------------------
__global__ __launch_bounds__(256) void rope_qk(
    bf16* __restrict__ Q, bf16* __restrict__ Kb,
    const float* __restrict__ FC, const float* __restrict__ FS)
{
  const int row = blockIdx.x;
  const int s = row & 1023;
  const int t = threadIdx.x;
  bf16* base = (blockIdx.y ? Kb : Q) + (long)row * 4096 + t * 16;
  short8 v0 = *(const short8*)base;
  short8 v1 = *(const short8*)(base + 8);
  const float* cp = FC + s * 64 + (t & 7) * 8;
  const float* sp = FS + s * 64 + (t & 7) * 8;
  f32x4 c0 = *(const f32x4*)cp;
  f32x4 c1 = *(const f32x4*)(cp + 4);
  f32x4 s0 = *(const f32x4*)sp;
  f32x4 s1 = *(const f32x4*)(sp + 4);
  short8 o0, o1;
#pragma unroll
  for (int j = 0; j < 4; j++) {
    float c = c0[j], sn = s0[j];
    float e = bf2f(v0[2 * j]), od = bf2f(v0[2 * j + 1]);
    o0[2 * j] = f2bf(e * c - od * sn);
    o0[2 * j + 1] = f2bf(e * sn + od * c);
    float c2 = c1[j], sn2 = s1[j];
    float e2 = bf2f(v1[2 * j]), od2 = bf2f(v1[2 * j + 1]);
    o1[2 * j] = f2bf(e2 * c2 - od2 * sn2);
    o1[2 * j + 1] = f2bf(e2 * sn2 + od2 * c2);
  }
  *(short8*)base = o0;
  *(short8*)(base + 8) = o1;
}

// ---------------------------------------------------------------------------
// V transpose: v[b][s][h][d] -> vT[bh][d][s]
// ---------------------------------------------------------------------------
__global__ __launch_bounds__(256) void transpose_v(
    const bf16* __restrict__ V, bf16* __restrict__ VT)
{
  __shared__ bf16 T[64 * 128];
  const int tid = threadIdx.x;
  const int st = blockIdx.x * 64, bh = blockIdx.y;
  const int b = bh >> 5, h = bh & 31;
  const bf16* src = V + ((long)(b * 1024 + st)) * 4096 + h * 128;
#pragma unroll
  for (int rr = 0; rr < 4; ++rr) {
    int i = tid + rr * 256;
    int s_l = i >> 4, c = i & 15;
    short8 v = *(const short8*)(src + (long)s_l * 4096 + c * 8);
    *(short8*)((char*)T + s_l * 256 + ((c ^ (s_l & 7)) * 16)) = v;
  }
  __syncthreads();
#pragma unroll
  for (int rr = 0; rr < 4; ++rr) {
    int i = tid + rr * 256;
    int d = i >> 3, cs = i & 7;
    short8 ov;
#pragma unroll
    for (int e = 0; e < 8; e++) {
      int s_l = cs * 8 + e;
      ov[e] = *(const short*)((char*)T + s_l * 256 + (((d >> 3) ^ (s_l & 7)) * 16) + (d & 7) * 2);
    }
    *(short8*)(VT + ((long)bh * 128 + d) * 1024 + st + cs * 8) = ov;
  }
}

// ---------------------------------------------------------------------------
// Flash attention, causal, + fused gated prompt attention. (round-6, bf16 out)
// ---------------------------------------------------------------------------
__global__ __launch_bounds__(256) void flash_attn(
    const bf16* __restrict__ Q, const bf16* __restrict__ Kg, const bf16* __restrict__ VT,
    const bf16* __restrict__ PK, const bf16* __restrict__ PV,
    const float* __restrict__ GATE, bf16* __restrict__ O)
{
  __shared__ bf16 Kl[32 * 128];
  __shared__ bf16 Vl[128 * 32];
  __shared__ bf16 PKl[16 * 128];
  __shared__ bf16 PVl[128 * 16];
  __shared__ bf16 Pl[4][16 * 32];
  const int tid = threadIdx.x, w = tid >> 6, l = tid & 63;
  const int lg = l >> 4, lr = l & 15;
  const int qb = blockIdx.x, bh = blockIdx.y;
  const int b = bh >> 5, h = bh & 31;
  const int q0 = qb * 64 + w * 16;

  short8 qf[4];
  {
    const bf16* qp = Q + ((long)(b * 1024 + q0 + lr)) * 4096 + h * 128 + lg * 8;
#pragma unroll
    for (int c = 0; c < 4; c++) qf[c] = *(const short8*)(qp + c * 32);
  }
  {
    int rowp = tid >> 4, pc = tid & 15, lc = pc ^ (rowp & 7);
    short8 v = {0, 0, 0, 0, 0, 0, 0, 0};
    if (rowp < 10) v = *(const short8*)(PK + (long)rowp * 4096 + h * 128 + lc * 8);
    *(short8*)((char*)PKl + tid * 16) = v;
  }
  {
    int d = tid >> 1, pb = (tid & 1) * 8;
#pragma unroll
    for (int e = 0; e < 8; e++) {
      int p = pb + e;
      short v = 0;
      if (p < 10) v = __builtin_bit_cast(short, PV[(long)p * 4096 + h * 128 + d]);
      *(short*)((char*)PVl + d * 32 + (((p >> 3) ^ (d & 1)) * 16) + (p & 7) * 2) = v;
    }
  }
  const float gate = GATE[h];

  f32x4 o[8];
#pragma unroll
  for (int i = 0; i < 8; i++) o[i] = (f32x4){0.f, 0.f, 0.f, 0.f};
  float m_[4] = {-1e30f, -1e30f, -1e30f, -1e30f};
  float l_[4] = {0.f, 0.f, 0.f, 0.f};

  const int nt = (qb + 1) * 2;
  const bf16* Kbase = Kg + ((long)b * 1024) * 4096 + h * 128;
  const bf16* Vbase = VT + ((long)bh) * 128 * 1024;
  const int cb1 = w * 64, cb2 = 256 + w * 64;
  const int iA = cb1 + l, iB = cb2 + l;
  bf16* pw = &Pl[w][0];

  for (int j = 0; j < nt; ++j) {
    __syncthreads();
    {
      const bf16* gA = Kbase + (long)(j * 32 + (iA >> 4)) * 4096 + ((iA & 15) ^ ((iA >> 4) & 7)) * 8;
      const bf16* gB = Kbase + (long)(j * 32 + (iB >> 4)) * 4096 + ((iB & 15) ^ ((iB >> 4) & 7)) * 8;
      gl_lds16(gA, Kl + cb1 * 8);
      gl_lds16(gB, Kl + cb2 * 8);
      const bf16* vA = Vbase + (long)(iA >> 2) * 1024 + j * 32 + ((iA & 3) ^ ((iA >> 2) & 3)) * 8;
      const bf16* vB = Vbase + (long)(iB >> 2) * 1024 + j * 32 + ((iB & 3) ^ ((iB >> 2) & 3)) * 8;
      gl_lds16(vA, Vl + cb1 * 8);
      gl_lds16(vB, Vl + cb2 * 8);
    }
    __syncthreads();

    f32x4 s[2];
#pragma unroll
    for (int ns = 0; ns < 2; ns++) {
      f32x4 a = (f32x4){0.f, 0.f, 0.f, 0.f};
      int krow = ns * 16 + lr;
      const char* kp = (const char*)Kl + krow * 256;
      int sw = krow & 7;
#pragma unroll
      for (int c = 0; c < 4; c++) {
        short8 kf = *(const short8*)(kp + (((c * 4 + lg) ^ sw) * 16));
        a = mfma16(qf[c], kf, a);
      }
      int key = j * 32 + krow;
#pragma unroll
      for (int r = 0; r < 4; r++) {
        int qr = q0 + lg * 4 + r;
        s[ns][r] = a[r] * SCALE_ + ((key <= qr) ? 0.0f : -1e30f);
      }
    }
    float mx[4], cor[4], sum[4];
#pragma unroll
    for (int r = 0; r < 4; r++) mx[r] = fmaxf(s[0][r], s[1][r]);
#pragma unroll
    for (int xm = 1; xm < 16; xm <<= 1)
#pragma unroll
      for (int r = 0; r < 4; r++) mx[r] = fmaxf(mx[r], __shfl_xor(mx[r], xm, 64));
#pragma unroll
    for (int r = 0; r < 4; r++) {
      float mn = fmaxf(m_[r], mx[r]);
      cor[r] = __expf(m_[r] - mn);
      m_[r] = mn;
      s[0][r] = __expf(s[0][r] - mn);
      s[1][r] = __expf(s[1][r] - mn);
      sum[r] = s[0][r] + s[1][r];
    }
#pragma unroll
    for (int xm = 1; xm < 16; xm <<= 1)
#pragma unroll
      for (int r = 0; r < 4; r++) sum[r] += __shfl_xor(sum[r], xm, 64);
#pragma unroll
    for (int r = 0; r < 4; r++) l_[r] = l_[r] * cor[r] + sum[r];
#pragma unroll
    for (int df = 0; df < 8; df++)
#pragma unroll
      for (int r = 0; r < 4; r++) o[df][r] *= cor[r];

#pragma unroll
    for (int ns = 0; ns < 2; ns++)
#pragma unroll
      for (int r = 0; r < 4; r++)
        *(short*)((char*)pw + ((lg * 4 + r) * 32 + ns * 16 + lr) * 2) = f2bf(s[ns][r]);
    asm volatile("s_waitcnt lgkmcnt(0)" ::: "memory");
    __builtin_amdgcn_sched_barrier(0);
    short8 pf = *(const short8*)(pw + lr * 32 + lg * 8);

#pragma unroll
    for (int df = 0; df < 8; df++) {
      int d = df * 16 + lr;
      short8 vf = *(const short8*)((const char*)Vl + d * 64 + ((lg ^ (d & 3)) * 16));
      o[df] = mfma16(pf, vf, o[df]);
    }
  }

  // ---- prompt attention ----
  f32x4 ps;
  {
    f32x4 a = (f32x4){0.f, 0.f, 0.f, 0.f};
    const char* kp = (const char*)PKl + lr * 256;
    int sw = lr & 7;
#pragma unroll
    for (int c = 0; c < 4; c++) {
      short8 kf = *(const short8*)(kp + (((c * 4 + lg) ^ sw) * 16));
      a = mfma16(qf[c], kf, a);
    }
#pragma unroll
    for (int r = 0; r < 4; r++) ps[r] = (lr < 10) ? a[r] * SCALE_ : -1e30f;
  }
  {
    float pm[4], pss[4];
#pragma unroll
    for (int r = 0; r < 4; r++) pm[r] = ps[r];
#pragma unroll
    for (int xm = 1; xm < 16; xm <<= 1)
#pragma unroll
      for (int r = 0; r < 4; r++) pm[r] = fmaxf(pm[r], __shfl_xor(pm[r], xm, 64));
#pragma unroll
    for (int r = 0; r < 4; r++) { ps[r] = __expf(ps[r] - pm[r]); pss[r] = ps[r]; }
#pragma unroll
    for (int xm = 1; xm < 16; xm <<= 1)
#pragma unroll
      for (int r = 0; r < 4; r++) pss[r] += __shfl_xor(pss[r], xm, 64);
#pragma unroll
    for (int r = 0; r < 4; r++) ps[r] = ps[r] / pss[r];
  }
#pragma unroll
  for (int r = 0; r < 4; r++) {
    *(short*)((char*)pw + ((lg * 4 + r) * 32 + lr) * 2) = f2bf(ps[r]);
    *(short*)((char*)pw + ((lg * 4 + r) * 32 + 16 + lr) * 2) = 0;
  }
  asm volatile("s_waitcnt lgkmcnt(0)" ::: "memory");
  __builtin_amdgcn_sched_barrier(0);
  short8 pf2 = *(const short8*)(pw + lr * 32 + lg * 8);
  f32x4 po[8];
#pragma unroll
  for (int df = 0; df < 8; df++) {
    int d = df * 16 + lr;
    short8 vf = {0, 0, 0, 0, 0, 0, 0, 0};
    if (lg < 2) vf = *(const short8*)((const char*)PVl + d * 32 + ((lg ^ (d & 1)) * 16));
    po[df] = mfma16(pf2, vf, (f32x4){0.f, 0.f, 0.f, 0.f});
  }

  bf16* op = O + ((long)(b * 1024 + q0 + lg * 4)) * 4096 + h * 128 + lr;
#pragma unroll
  for (int df = 0; df < 8; df++)
#pragma unroll
    for (int r = 0; r < 4; r++) {
      float val = o[df][r] / l_[r] + gate * po[df][r];
      *(short*)(op + (long)r * 4096 + df * 16) = f2bf(val);
    }
}

// ---------------------------------------------------------------------------
extern "C" void kernel_launch(void* const* d_in, const int* in_sizes, int n_in,
                              void* d_out, int out_size, void* d_ws, size_t ws_size,
                              hipStream_t stream) {
  (void)in_sizes; (void)n_in; (void)out_size; (void)ws_size;
  const float* x      = (const float*)d_in[0];
  const float* wq     = (const float*)d_in[1];
  const float* wk     = (const float*)d_in[2];
  const float* wv     = (const float*)d_in[3];
  const float* wo     = (const float*)d_in[4];
  const float* prompt = (const float*)d_in[5];
  const float* gate   = (const float*)d_in[6];
  const float* fcos   = (const float*)d_in[7];
  const float* fsin   = (const float*)d_in[8];
  float* out = (float*)d_out;
  char* ws = (char*)d_ws;

  size_t o = 0;
  bf16* xb  = (bf16*)(ws + o); o += (size_t)8388608 * 2;
  bf16* wqb = (bf16*)(ws + o); o += (size_t)16777216 * 2;
  bf16* wkb = (bf16*)(ws + o); o += (size_t)16777216 * 2;
  bf16* wvb = (bf16*)(ws + o); o += (size_t)16777216 * 2;
  bf16* wob = (bf16*)(ws + o); o += (size_t)16777216 * 2;
  bf16* pb  = (bf16*)(ws + o); o += (size_t)40960 * 2;
  bf16* q_ws  = (bf16*)(ws + o); o += (size_t)2048 * 4096 * 2;
  bf16* k_ws  = (bf16*)(ws + o); o += (size_t)2048 * 4096 * 2;
  bf16* v_ws  = (bf16*)(ws + o); o += (size_t)2048 * 4096 * 2;
  bf16* vT_ws = (bf16*)(ws + o); o += (size_t)2048 * 4096 * 2;
  bf16* pk_ws = (bf16*)(ws + o); o += (size_t)40960 * 2;
  bf16* pv_ws = (bf16*)(ws + o); o += (size_t)40960 * 2;
  bf16* attn_ws = v_ws;
  // K-split f32 partials overlay buffers dead by out-proj time:
  // p0 over q_ws+k_ws (33.55MB), p1 over xb+wqb (50MB available).
  float* p0 = (float*)q_ws;
  float* p1 = (float*)xb;

  // 1. downcast inputs to bf16
  cvt6<<<dim3(36884), 256, 0, stream>>>(x, wq, wk, wv, wo, prompt,
                                        xb, wqb, wkb, wvb, wob, pb);
  // 2. QKV (+prompt K/V rows): 9 m-tiles x 16 n-tiles per z
  gemm_bt<64, false><<<dim3(144, 1, 3), 512, 0, stream>>>(
      xb, pb, wqb, wkb, wvb, q_ws, k_ws, v_ws, pk_ws, pv_ws, (float*)0, 2048, 2058);
  // 3. RoPE on q, k
  rope_qk<<<dim3(2048, 2), 256, 0, stream>>>(q_ws, k_ws, fcos, fsin);
  // 4. V -> VT
  transpose_v<<<dim3(16, 64), 256, 0, stream>>>(v_ws, vT_ws);
  // 5. flash attention + gated prompt attention (bf16 out into v_ws)
  flash_attn<<<dim3(16, 64), 256, 0, stream>>>(
      q_ws, k_ws, vT_ws, pk_ws, pv_ws, gate, attn_ws);
  // 6. output projection, K-split z=2 (256 blocks -> full occupancy),
  //    f32 partials p0/p1, then combine.
  gemm_bt<32, true><<<dim3(128, 1, 2), 512, 0, stream>>>(
      attn_ws, attn_ws, wob, wob, wob, (bf16*)0, (bf16*)0, (bf16*)0,
      (bf16*)0, (bf16*)0, p0, 2048, 2048);
  addf<<<dim3(8192), 256, 0, stream>>>(p0, p0 + (size_t)2048 * 4096, out);
}

// Round 9
// 508.304 us; speedup vs baseline: 1.1271x; 1.0327x over previous
//
#include <hip/hip_runtime.h>
#include <hip/hip_bf16.h>
#include <stdint.h>

typedef __hip_bfloat16 bf16;
typedef __attribute__((ext_vector_type(8))) short short8;
typedef __attribute__((ext_vector_type(4))) float f32x4;

#define SCALE_ 0.08838834764831845f  // 1/sqrt(128)

static __device__ __forceinline__ float bf2f(short u) {
  unsigned int x = ((unsigned int)(unsigned short)u) << 16;
  return __builtin_bit_cast(float, x);
}
static __device__ __forceinline__ short f2bf(float f) {
  __hip_bfloat16 h = __float2bfloat16(f);
  return __builtin_bit_cast(short, h);
}
static __device__ __forceinline__ f32x4 mfma16(short8 a, short8 b, f32x4 c) {
  return __builtin_amdgcn_mfma_f32_16x16x32_bf16(a, b, c, 0, 0, 0);
}
static __device__ __forceinline__ void gl_lds16(const bf16* g, bf16* l) {
  __builtin_amdgcn_global_load_lds(
      (const __attribute__((address_space(1))) unsigned int*)g,
      (__attribute__((address_space(3))) unsigned int*)l, 16, 0, 0);
}

// ---------------------------------------------------------------------------
// f32 -> bf16 conversion for x, wq, wk, wv, wo, prompt (one fused launch).
// ---------------------------------------------------------------------------
__global__ __launch_bounds__(256) void cvt6(
    const float* __restrict__ sx, const float* __restrict__ sq,
    const float* __restrict__ sk, const float* __restrict__ sv,
    const float* __restrict__ so, const float* __restrict__ sp,
    bf16* __restrict__ dx, bf16* __restrict__ dq, bf16* __restrict__ dk,
    bf16* __restrict__ dv, bf16* __restrict__ d4, bf16* __restrict__ dp)
{
  int b = blockIdx.x;
  const float* s; bf16* d; int off;
  if (b < 4096)       { s = sx; d = dx; off = b; }
  else if (b < 12288) { s = sq; d = dq; off = b - 4096; }
  else if (b < 20480) { s = sk; d = dk; off = b - 12288; }
  else if (b < 28672) { s = sv; d = dv; off = b - 20480; }
  else if (b < 36864) { s = so; d = d4; off = b - 28672; }
  else                { s = sp; d = dp; off = b - 36864; }
  long base = (long)off * 2048 + threadIdx.x * 8;
  f32x4 a = *(const f32x4*)(s + base);
  f32x4 c = *(const f32x4*)(s + base + 4);
  short8 o;
#pragma unroll
  for (int j = 0; j < 4; j++) { o[j] = f2bf(a[j]); o[4 + j] = f2bf(c[j]); }
  *(short8*)(d + base) = o;
}

// ---------------------------------------------------------------------------
// QKV GEMM (round-6/8 verified structure, unchanged):
// 256x256 tile, BK=64, 8 waves (2m x 4n), 8-phase DEPTH-6, vmcnt(8) @ p0/p2.
// ---------------------------------------------------------------------------
template <int NKT, bool KSPLIT>
__global__ __launch_bounds__(512, 2) void gemm_bt(
    const bf16* __restrict__ A, const bf16* __restrict__ A2,
    const bf16* __restrict__ B0, const bf16* __restrict__ B1, const bf16* __restrict__ B2w,
    bf16* __restrict__ C0, bf16* __restrict__ C1, bf16* __restrict__ C2,
    bf16* __restrict__ P1, bf16* __restrict__ P2,
    float* __restrict__ CF,
    int M1, int Mtot)
{
  __shared__ char lds[131072];   // 8 slots x 16KB
  const int tid = threadIdx.x, w = tid >> 6, l = tid & 63;
  const int lr = l & 15, lg = l >> 4;
  const int wm = w >> 2, wn = w & 3;
  const int z = blockIdx.z;
  const bf16* Bw = KSPLIT ? B0 : ((z == 0) ? B0 : ((z == 1) ? B1 : B2w));
  bf16* C  = (z == 0) ? C0 : ((z == 1) ? C1 : C2);
  bf16* Cp = (KSPLIT || z == 0) ? (bf16*)0 : ((z == 1) ? P1 : P2);
  float* CFz = CF;
  long koff = 0;
  if (KSPLIT) { koff = (long)z * NKT * 64; CFz = CF + (long)z * M1 * 4096; }

  const int cpx = gridDim.x >> 3, orig = blockIdx.x;
  const int wg = (orig & 7) * cpx + (orig >> 3);
  const long m0 = (long)(wg >> 4) * 256;
  const long n0 = (long)(wg & 15) * 256;

  const int r0 = ((tid >> 3) << 1) | ((tid >> 2) & 1);
  const int c0 = (tid & 3) ^ ((tid >> 3) & 3);
  const bf16 *pa0, *pa1;
  {
    long mx = (long)(Mtot - M1) - 1;
    long g0 = m0 + r0, g1 = m0 + r0 + 128;
    const bf16 *q0, *q1;
    if (g0 < M1) q0 = A + g0 * 4096;
    else { long rr = g0 - M1; if (rr > mx) rr = mx; q0 = A2 + rr * 4096; }
    if (g1 < M1) q1 = A + g1 * 4096;
    else { long rr = g1 - M1; if (rr > mx) rr = mx; q1 = A2 + rr * 4096; }
    pa0 = q0 + c0 * 8 + koff;
    pa1 = q1 + c0 * 8 + koff;
  }
  const bf16* pb0 = Bw + (n0 + r0) * 4096 + c0 * 8 + koff;
  const bf16* pb1 = pb0 + (long)128 * 4096;

  const int ro  = (lr >> 1) * 128 + (((lr & 1) * 4) + (lg ^ ((lr >> 1) & 3))) * 16;
  const int aro = wm * 8192 + ro;
  const int bro = wn * 4096 + ro;

  f32x4 acc[8][4];
#pragma unroll
  for (int i = 0; i < 8; i++)
#pragma unroll
    for (int j = 0; j < 4; j++) acc[i][j] = (f32x4){0.f, 0.f, 0.f, 0.f};

  short8 af[4], bf[4];

#define STGA(S_, KE_)                                                        \
  {                                                                          \
    bf16* d_ = (bf16*)(lds + (S_) * 16384) + tid * 8;                        \
    gl_lds16(pa0 + (KE_), d_);                                               \
    gl_lds16(pa1 + (KE_), d_ + 4096);                                        \
  }
#define STGB(S_, KE_)                                                        \
  {                                                                          \
    bf16* d_ = (bf16*)(lds + (S_) * 16384) + tid * 8;                        \
    gl_lds16(pb0 + (KE_), d_);                                               \
    gl_lds16(pb1 + (KE_), d_ + 4096);                                        \
  }
#define SYNC(VM_)                                                            \
  {                                                                          \
    asm volatile("s_waitcnt vmcnt(" VM_ ")" ::: "memory");                   \
    __builtin_amdgcn_s_barrier();                                            \
    __builtin_amdgcn_sched_barrier(0);                                       \
  }
#define PHASE(PRB_, AU_, BU_, MO_, LB_, STG_)                                \
  {                                                                          \
    STG_                                                                     \
    const char* ab_ = lds + (PRB_) + (AU_) + aro;                            \
    _Pragma("unroll") for (int mi = 0; mi < 4; mi++)                         \
      af[mi] = *(const short8*)(ab_ + ((MO_) + mi) * 1024);                  \
    if (LB_) {                                                               \
      const char* bb_ = lds + (PRB_) + (BU_) + bro;                          \
      _Pragma("unroll") for (int ni = 0; ni < 4; ni++)                       \
        bf[ni] = *(const short8*)(bb_ + ni * 1024);                          \
    }                                                                        \
    asm volatile("s_waitcnt lgkmcnt(0)" ::: "memory");                       \
    __builtin_amdgcn_sched_barrier(0);                                       \
    __builtin_amdgcn_s_setprio(1);                                           \
    _Pragma("unroll") for (int mi = 0; mi < 4; mi++)                         \
      _Pragma("unroll") for (int ni = 0; ni < 4; ni++)                       \
        acc[(MO_) + mi][ni] = mfma16(af[mi], bf[ni], acc[(MO_) + mi][ni]);   \
    __builtin_amdgcn_s_setprio(0);                                           \
  }
#define KT(PRB_, S6_, S7_, S8_, S9_, KE1_, KE2_)                             \
  SYNC("8") PHASE(PRB_, 0, 16384, 0, 1, STGA(S6_, KE1_))                     \
  PHASE(PRB_, 0, 16384, 4, 0, STGB(S7_, KE1_))                               \
  SYNC("8") PHASE(PRB_, 32768, 49152, 0, 1, STGA(S8_, KE2_))                 \
  PHASE(PRB_, 32768, 49152, 4, 0, STGB(S9_, KE2_))

  STGA(0, 0) STGB(1, 0) STGA(2, 32) STGB(3, 32) STGA(4, 64) STGB(5, 64)

  for (int t = 0; t < NKT - 2; t += 2) {
    const int ka = (t + 1) * 64 + 32, kb = (t + 2) * 64;
    const int kc = (t + 2) * 64 + 32, kd = (t + 3) * 64;
    KT(0, 6, 7, 0, 1, ka, kb)
    KT(65536, 2, 3, 4, 5, kc, kd)
  }
  {
    const int kel = (NKT - 1) * 64 + 32;
    SYNC("8") PHASE(0, 0, 16384, 0, 1, STGA(6, kel))
    PHASE(0, 0, 16384, 4, 0, STGB(7, kel))
    SYNC("8") PHASE(0, 32768, 49152, 0, 1, )
    PHASE(0, 32768, 49152, 4, 0, )
  }
  SYNC("4") PHASE(65536, 0, 16384, 0, 1, )
  PHASE(65536, 0, 16384, 4, 0, )
  SYNC("0") PHASE(65536, 32768, 49152, 0, 1, )
  PHASE(65536, 32768, 49152, 4, 0, )

#undef KT
#undef PHASE
#undef SYNC
#undef STGB
#undef STGA

#pragma unroll
  for (int mi = 0; mi < 8; mi++) {
#pragma unroll
    for (int ni = 0; ni < 4; ni++) {
      long col = n0 + wn * 64 + ni * 16 + lr;
      f32x4 v = acc[mi][ni];
#pragma unroll
      for (int j = 0; j < 4; j++) {
        long row = m0 + wm * 128 + mi * 16 + lg * 4 + j;
        if (CFz) {
          CFz[row * 4096 + col] = v[j];
        } else if (row < M1) {
          *(short*)(C + row * 4096 + col) = f2bf(v[j]);
        } else if (Cp != 0 && row < Mtot) {
          *(short*)(Cp + (row - M1) * 4096 + col) = f2bf(v[j]);
        }
      }
    }
  }
}

// ---------------------------------------------------------------------------
// Out-projection GEMM, N-split shape: 256x128 tile, BK=64, 8 waves (4m x 2n),
// per-wave 64x64 (acc 4x4). 2 phases/K-tile; unit u: t=u>>2, type u&3 in
// {A0(2 loads,16KB), B0(1 load,8KB), A1, B1}; slot ring = 2 parities x
// {A0@0, B0@16K, A1@24K, B1@40K} = 96KB LDS. Phase g stages units 2g+4,2g+5
// and reads 2g,2g+1 after vmcnt(3) (outstanding = next tile's A+B = 3 loads
// -> certifies exactly the units read; 2-phase ~1400cy slack). Barrier every
// phase; WAR slot-reuse distance = 4 phases. Same LDS micro-layout + swizzle
// + ro formula as gemm_bt (A unit identical; B unit = A's first 8KB half).
// M=2048 (no prompt rows), f32 output direct.
// ---------------------------------------------------------------------------
__global__ __launch_bounds__(512, 2) void gemm_n128(
    const bf16* __restrict__ A, const bf16* __restrict__ Bw,
    float* __restrict__ CF)
{
  __shared__ char lds[98304];   // 2 parities x 48KB
  const int tid = threadIdx.x, w = tid >> 6, l = tid & 63;
  const int lr = l & 15, lg = l >> 4;
  const int wm = w >> 1, wn = w & 1;

  // T1 swizzle: 256 blocks, n fastest (32 n-tiles per m-row -> A shared
  // by all concurrent blocks of an XCD).
  const int cpx = gridDim.x >> 3, orig = blockIdx.x;
  const int wg = (orig & 7) * cpx + (orig >> 3);
  const long m0 = (long)(wg >> 5) * 256;
  const long n0 = (long)(wg & 31) * 128;

  const int r0 = ((tid >> 3) << 1) | ((tid >> 2) & 1);   // [0,128)
  const int c0 = (tid & 3) ^ ((tid >> 3) & 3);
  const bf16* pa0 = A + (m0 + r0) * 4096 + c0 * 8;
  const bf16* pa1 = pa0 + (long)128 * 4096;
  const bf16* pb0 = Bw + (n0 + r0) * 4096 + c0 * 8;

  const int ro  = (lr >> 1) * 128 + (((lr & 1) * 4) + (lg ^ ((lr >> 1) & 3))) * 16;
  const int aro = wm * 4096 + ro;   // + mi*1024 (wm in [0,4))
  const int bro = wn * 4096 + ro;   // + ni*1024 (wn in [0,2))

  f32x4 acc[4][4];
#pragma unroll
  for (int i = 0; i < 4; i++)
#pragma unroll
    for (int j = 0; j < 4; j++) acc[i][j] = (f32x4){0.f, 0.f, 0.f, 0.f};

  short8 af[4], bf[4];

#define NSTGA(SB_, KE_)                                                      \
  {                                                                          \
    bf16* d_ = (bf16*)(lds + (SB_)) + tid * 8;                               \
    gl_lds16(pa0 + (KE_), d_);                                               \
    gl_lds16(pa1 + (KE_), d_ + 4096);                                        \
  }
#define NSTGB(SB_, KE_)                                                      \
  {                                                                          \
    bf16* d_ = (bf16*)(lds + (SB_)) + tid * 8;                               \
    gl_lds16(pb0 + (KE_), d_);                                               \
  }
#define NSYNC(VM_)                                                           \
  {                                                                          \
    asm volatile("s_waitcnt vmcnt(" VM_ ")" ::: "memory");                   \
    __builtin_amdgcn_s_barrier();                                            \
    __builtin_amdgcn_sched_barrier(0);                                       \
  }
// one phase: read A-unit @PRB_+AO_, B-unit @PRB_+BO_, 16 MFMA
#define NPH(PRB_, AO_, BO_, STG_)                                            \
  {                                                                          \
    STG_                                                                     \
    const char* ab_ = lds + (PRB_) + (AO_) + aro;                            \
    _Pragma("unroll") for (int mi = 0; mi < 4; mi++)                         \
      af[mi] = *(const short8*)(ab_ + mi * 1024);                            \
    const char* bb_ = lds + (PRB_) + (BO_) + bro;                            \
    _Pragma("unroll") for (int ni = 0; ni < 4; ni++)                         \
      bf[ni] = *(const short8*)(bb_ + ni * 1024);                            \
    asm volatile("s_waitcnt lgkmcnt(0)" ::: "memory");                       \
    __builtin_amdgcn_sched_barrier(0);                                       \
    __builtin_amdgcn_s_setprio(1);                                           \
    _Pragma("unroll") for (int mi = 0; mi < 4; mi++)                         \
      _Pragma("unroll") for (int ni = 0; ni < 4; ni++)                       \
        acc[mi][ni] = mfma16(af[mi], bf[ni], acc[mi][ni]);                   \
    __builtin_amdgcn_s_setprio(0);                                           \
  }

  // prologue: units 0..5  (tile0 A0,B0,A1,B1 ; tile1 A0,B0) -> 9 loads
  NSTGA(0, 0)      NSTGB(16384, 0)
  NSTGA(24576, 32) NSTGB(40960, 32)
  NSTGA(49152, 64) NSTGB(65536, 64)

  // tiles 0..61 (pairs); tile t even reads parity0, stages into parity1
  for (int t = 0; t < 62; t += 2) {
    const int ka = (t + 1) * 64 + 32;  // A1/B1 of tile t+1
    const int kb = (t + 2) * 64;       // A0/B0 of tile t+2
    NSYNC("3") NPH(0, 0, 16384,     NSTGA(49152 + 24576, ka) NSTGB(49152 + 40960, ka))
    NSYNC("3") NPH(0, 24576, 40960, NSTGA(0, kb) NSTGB(16384, kb))
    const int kc = (t + 2) * 64 + 32;  // A1/B1 of tile t+2
    const int kd = (t + 3) * 64;       // A0/B0 of tile t+3
    NSYNC("3") NPH(49152, 0, 16384,     NSTGA(24576, kc) NSTGB(40960, kc))
    NSYNC("3") NPH(49152, 24576, 40960, NSTGA(49152, kd) NSTGB(49152 + 16384, kd))
  }
  // tile 62 (parity 0): stage tile 63's units into parity 1
  NSYNC("3") NPH(0, 0, 16384,     NSTGA(49152 + 24576, 63 * 64 + 32) NSTGB(49152 + 40960, 63 * 64 + 32))
  NSYNC("3") NPH(0, 24576, 40960, )
  // tile 63 (parity 1): drain
  NSYNC("3") NPH(49152, 0, 16384, )
  NSYNC("0") NPH(49152, 24576, 40960, )

#undef NPH
#undef NSYNC
#undef NSTGB
#undef NSTGA

  // epilogue: f32 direct
#pragma unroll
  for (int mi = 0; mi < 4; mi++) {
#pragma unroll
    for (int ni = 0; ni < 4; ni++) {
      long col = n0 + wn * 64 + ni * 16 + lr;
      f32x4 v = acc[mi][ni];
#pragma unroll
      for (int j = 0; j < 4; j++) {
        long row = m0 + wm * 64 + mi * 16 + lg * 4 + j;
        CF[row * 4096 + col] = v[j];
      }
    }
  }
}

// ---------------------------------------------------------------------------
// Merged RoPE (q,k) + V transpose: grid (2048, 3).
// y<2: rope row x of Q/K. y==2, x<1024: transpose tile (x&15, x>>4).
// ---------------------------------------------------------------------------
__global__ __launch_bounds__(256) void prep_qkv(
    bf16* __restrict__ Q, bf16* __restrict__ Kb,
    const float* __restrict__ FC, const float* __restrict__ FS,
    const bf16* __restrict__ V, bf16* __restrict__ VT)
{
  const int t = threadIdx.x;
  if (blockIdx.y < 2) {
    const int row = blockIdx.x;
    const int s = row & 1023;
    bf16* base = (blockIdx.y ? Kb : Q) + (long)row * 4096 + t * 16;
    short8 v0 = *(const short8*)base;
    short8 v1 = *(const short8*)(base + 8);
    const float* cp = FC + s * 64 + (t & 7) * 8;
    const float* sp = FS + s * 64 + (t & 7) * 8;
    f32x4 c0 = *(const f32x4*)cp;
    f32x4 c1 = *(const f32x4*)(cp + 4);
    f32x4 s0 = *(const f32x4*)sp;
    f32x4 s1 = *(const f32x4*)(sp + 4);
    short8 o0, o1;
#pragma unroll
    for (int j = 0; j < 4; j++) {
      float c = c0[j], sn = s0[j];
      float e = bf2f(v0[2 * j]), od = bf2f(v0[2 * j + 1]);
      o0[2 * j] = f2bf(e * c - od * sn);
      o0[2 * j + 1] = f2bf(e * sn + od * c);
      float c2 = c1[j], sn2 = s1[j];
      float e2 = bf2f(v1[2 * j]), od2 = bf2f(v1[2 * j + 1]);
      o1[2 * j] = f2bf(e2 * c2 - od2 * sn2);
      o1[2 * j + 1] = f2bf(e2 * sn2 + od2 * c2);
    }
    *(short8*)base = o0;
    *(short8*)(base + 8) = o1;
    return;
  }
  if (blockIdx.x >= 1024) return;
  __shared__ bf16 T[64 * 128];
  const int st = (blockIdx.x & 15) * 64, bh = blockIdx.x >> 4;
  const int b = bh >> 5, h = bh & 31;
  const bf16* src = V + ((long)(b * 1024 + st)) * 4096 + h * 128;
#pragma unroll
  for (int rr = 0; rr < 4; ++rr) {
    int i = t + rr * 256;
    int s_l = i >> 4, c = i & 15;
    short8 v = *(const short8*)(src + (long)s_l * 4096 + c * 8);
    *(short8*)((char*)T + s_l * 256 + ((c ^ (s_l & 7)) * 16)) = v;
  }
  __syncthreads();
#pragma unroll
  for (int rr = 0; rr < 4; ++rr) {
    int i = t + rr * 256;
    int d = i >> 3, cs = i & 7;
    short8 ov;
#pragma unroll
    for (int e = 0; e < 8; e++) {
      int s_l = cs * 8 + e;
      ov[e] = *(const short*)((char*)T + s_l * 256 + (((d >> 3) ^ (s_l & 7)) * 16) + (d & 7) * 2);
    }
    *(short8*)(VT + ((long)bh * 128 + d) * 1024 + st + cs * 8) = ov;
  }
}

// ---------------------------------------------------------------------------
// Flash attention, causal, + fused gated prompt attention. (unchanged)
// ---------------------------------------------------------------------------
__global__ __launch_bounds__(256) void flash_attn(
    const bf16* __restrict__ Q, const bf16* __restrict__ Kg, const bf16* __restrict__ VT,
    const bf16* __restrict__ PK, const bf16* __restrict__ PV,
    const float* __restrict__ GATE, bf16* __restrict__ O)
{
  __shared__ bf16 Kl[32 * 128];
  __shared__ bf16 Vl[128 * 32];
  __shared__ bf16 PKl[16 * 128];
  __shared__ bf16 PVl[128 * 16];
  __shared__ bf16 Pl[4][16 * 32];
  const int tid = threadIdx.x, w = tid >> 6, l = tid & 63;
  const int lg = l >> 4, lr = l & 15;
  const int qb = blockIdx.x, bh = blockIdx.y;
  const int b = bh >> 5, h = bh & 31;
  const int q0 = qb * 64 + w * 16;

  short8 qf[4];
  {
    const bf16* qp = Q + ((long)(b * 1024 + q0 + lr)) * 4096 + h * 128 + lg * 8;
#pragma unroll
    for (int c = 0; c < 4; c++) qf[c] = *(const short8*)(qp + c * 32);
  }
  {
    int rowp = tid >> 4, pc = tid & 15, lc = pc ^ (rowp & 7);
    short8 v = {0, 0, 0, 0, 0, 0, 0, 0};
    if (rowp < 10) v = *(const short8*)(PK + (long)rowp * 4096 + h * 128 + lc * 8);
    *(short8*)((char*)PKl + tid * 16) = v;
  }
  {
    int d = tid >> 1, pb = (tid & 1) * 8;
#pragma unroll
    for (int e = 0; e < 8; e++) {
      int p = pb + e;
      short v = 0;
      if (p < 10) v = __builtin_bit_cast(short, PV[(long)p * 4096 + h * 128 + d]);
      *(short*)((char*)PVl + d * 32 + (((p >> 3) ^ (d & 1)) * 16) + (p & 7) * 2) = v;
    }
  }
  const float gate = GATE[h];

  f32x4 o[8];
#pragma unroll
  for (int i = 0; i < 8; i++) o[i] = (f32x4){0.f, 0.f, 0.f, 0.f};
  float m_[4] = {-1e30f, -1e30f, -1e30f, -1e30f};
  float l_[4] = {0.f, 0.f, 0.f, 0.f};

  const int nt = (qb + 1) * 2;
  const bf16* Kbase = Kg + ((long)b * 1024) * 4096 + h * 128;
  const bf16* Vbase = VT + ((long)bh) * 128 * 1024;
  const int cb1 = w * 64, cb2 = 256 + w * 64;
  const int iA = cb1 + l, iB = cb2 + l;
  bf16* pw = &Pl[w][0];

  for (int j = 0; j < nt; ++j) {
    __syncthreads();
    {
      const bf16* gA = Kbase + (long)(j * 32 + (iA >> 4)) * 4096 + ((iA & 15) ^ ((iA >> 4) & 7)) * 8;
      const bf16* gB = Kbase + (long)(j * 32 + (iB >> 4)) * 4096 + ((iB & 15) ^ ((iB >> 4) & 7)) * 8;
      gl_lds16(gA, Kl + cb1 * 8);
      gl_lds16(gB, Kl + cb2 * 8);
      const bf16* vA = Vbase + (long)(iA >> 2) * 1024 + j * 32 + ((iA & 3) ^ ((iA >> 2) & 3)) * 8;
      const bf16* vB = Vbase + (long)(iB >> 2) * 1024 + j * 32 + ((iB & 3) ^ ((iB >> 2) & 3)) * 8;
      gl_lds16(vA, Vl + cb1 * 8);
      gl_lds16(vB, Vl + cb2 * 8);
    }
    __syncthreads();

    f32x4 s[2];
#pragma unroll
    for (int ns = 0; ns < 2; ns++) {
      f32x4 a = (f32x4){0.f, 0.f, 0.f, 0.f};
      int krow = ns * 16 + lr;
      const char* kp = (const char*)Kl + krow * 256;
      int sw = krow & 7;
#pragma unroll
      for (int c = 0; c < 4; c++) {
        short8 kf = *(const short8*)(kp + (((c * 4 + lg) ^ sw) * 16));
        a = mfma16(qf[c], kf, a);
      }
      int key = j * 32 + krow;
#pragma unroll
      for (int r = 0; r < 4; r++) {
        int qr = q0 + lg * 4 + r;
        s[ns][r] = a[r] * SCALE_ + ((key <= qr) ? 0.0f : -1e30f);
      }
    }
    float mx[4], cor[4], sum[4];
#pragma unroll
    for (int r = 0; r < 4; r++) mx[r] = fmaxf(s[0][r], s[1][r]);
#pragma unroll
    for (int xm = 1; xm < 16; xm <<= 1)
#pragma unroll
      for (int r = 0; r < 4; r++) mx[r] = fmaxf(mx[r], __shfl_xor(mx[r], xm, 64));
#pragma unroll
    for (int r = 0; r < 4; r++) {
      float mn = fmaxf(m_[r], mx[r]);
      cor[r] = __expf(m_[r] - mn);
      m_[r] = mn;
      s[0][r] = __expf(s[0][r] - mn);
      s[1][r] = __expf(s[1][r] - mn);
      sum[r] = s[0][r] + s[1][r];
    }
#pragma unroll
    for (int xm = 1; xm < 16; xm <<= 1)
#pragma unroll
      for (int r = 0; r < 4; r++) sum[r] += __shfl_xor(sum[r], xm, 64);
#pragma unroll
    for (int r = 0; r < 4; r++) l_[r] = l_[r] * cor[r] + sum[r];
#pragma unroll
    for (int df = 0; df < 8; df++)
#pragma unroll
      for (int r = 0; r < 4; r++) o[df][r] *= cor[r];

#pragma unroll
    for (int ns = 0; ns < 2; ns++)
#pragma unroll
      for (int r = 0; r < 4; r++)
        *(short*)((char*)pw + ((lg * 4 + r) * 32 + ns * 16 + lr) * 2) = f2bf(s[ns][r]);
    asm volatile("s_waitcnt lgkmcnt(0)" ::: "memory");
    __builtin_amdgcn_sched_barrier(0);
    short8 pf = *(const short8*)(pw + lr * 32 + lg * 8);

#pragma unroll
    for (int df = 0; df < 8; df++) {
      int d = df * 16 + lr;
      short8 vf = *(const short8*)((const char*)Vl + d * 64 + ((lg ^ (d & 3)) * 16));
      o[df] = mfma16(pf, vf, o[df]);
    }
  }

  // ---- prompt attention ----
  f32x4 ps;
  {
    f32x4 a = (f32x4){0.f, 0.f, 0.f, 0.f};
    const char* kp = (const char*)PKl + lr * 256;
    int sw = lr & 7;
#pragma unroll
    for (int c = 0; c < 4; c++) {
      short8 kf = *(const short8*)(kp + (((c * 4 + lg) ^ sw) * 16));
      a = mfma16(qf[c], kf, a);
    }
#pragma unroll
    for (int r = 0; r < 4; r++) ps[r] = (lr < 10) ? a[r] * SCALE_ : -1e30f;
  }
  {
    float pm[4], pss[4];
#pragma unroll
    for (int r = 0; r < 4; r++) pm[r] = ps[r];
#pragma unroll
    for (int xm = 1; xm < 16; xm <<= 1)
#pragma unroll
      for (int r = 0; r < 4; r++) pm[r] = fmaxf(pm[r], __shfl_xor(pm[r], xm, 64));
#pragma unroll
    for (int r = 0; r < 4; r++) { ps[r] = __expf(ps[r] - pm[r]); pss[r] = ps[r]; }
#pragma unroll
    for (int xm = 1; xm < 16; xm <<= 1)
#pragma unroll
      for (int r = 0; r < 4; r++) pss[r] += __shfl_xor(pss[r], xm, 64);
#pragma unroll
    for (int r = 0; r < 4; r++) ps[r] = ps[r] / pss[r];
  }
#pragma unroll
  for (int r = 0; r < 4; r++) {
    *(short*)((char*)pw + ((lg * 4 + r) * 32 + lr) * 2) = f2bf(ps[r]);
    *(short*)((char*)pw + ((lg * 4 + r) * 32 + 16 + lr) * 2) = 0;
  }
  asm volatile("s_waitcnt lgkmcnt(0)" ::: "memory");
  __builtin_amdgcn_sched_barrier(0);
  short8 pf2 = *(const short8*)(pw + lr * 32 + lg * 8);
  f32x4 po[8];
#pragma unroll
  for (int df = 0; df < 8; df++) {
    int d = df * 16 + lr;
    short8 vf = {0, 0, 0, 0, 0, 0, 0, 0};
    if (lg < 2) vf = *(const short8*)((const char*)PVl + d * 32 + ((lg ^ (d & 1)) * 16));
    po[df] = mfma16(pf2, vf, (f32x4){0.f, 0.f, 0.f, 0.f});
  }

  bf16* op = O + ((long)(b * 1024 + q0 + lg * 4)) * 4096 + h * 128 + lr;
#pragma unroll
  for (int df = 0; df < 8; df++)
#pragma unroll
    for (int r = 0; r < 4; r++) {
      float val = o[df][r] / l_[r] + gate * po[df][r];
      *(short*)(op + (long)r * 4096 + df * 16) = f2bf(val);
    }
}

// ---------------------------------------------------------------------------
extern "C" void kernel_launch(void* const* d_in, const int* in_sizes, int n_in,
                              void* d_out, int out_size, void* d_ws, size_t ws_size,
                              hipStream_t stream) {
  (void)in_sizes; (void)n_in; (void)out_size; (void)ws_size;
  const float* x      = (const float*)d_in[0];
  const float* wq     = (const float*)d_in[1];
  const float* wk     = (const float*)d_in[2];
  const float* wv     = (const float*)d_in[3];
  const float* wo     = (const float*)d_in[4];
  const float* prompt = (const float*)d_in[5];
  const float* gate   = (const float*)d_in[6];
  const float* fcos   = (const float*)d_in[7];
  const float* fsin   = (const float*)d_in[8];
  float* out = (float*)d_out;
  char* ws = (char*)d_ws;

  size_t o = 0;
  bf16* xb  = (bf16*)(ws + o); o += (size_t)8388608 * 2;
  bf16* wqb = (bf16*)(ws + o); o += (size_t)16777216 * 2;
  bf16* wkb = (bf16*)(ws + o); o += (size_t)16777216 * 2;
  bf16* wvb = (bf16*)(ws + o); o += (size_t)16777216 * 2;
  bf16* wob = (bf16*)(ws + o); o += (size_t)16777216 * 2;
  bf16* pb  = (bf16*)(ws + o); o += (size_t)40960 * 2;
  bf16* q_ws  = (bf16*)(ws + o); o += (size_t)2048 * 4096 * 2;
  bf16* k_ws  = (bf16*)(ws + o); o += (size_t)2048 * 4096 * 2;
  bf16* v_ws  = (bf16*)(ws + o); o += (size_t)2048 * 4096 * 2;
  bf16* vT_ws = (bf16*)(ws + o); o += (size_t)2048 * 4096 * 2;
  bf16* pk_ws = (bf16*)(ws + o); o += (size_t)40960 * 2;
  bf16* pv_ws = (bf16*)(ws + o); o += (size_t)40960 * 2;
  bf16* attn_ws = v_ws;

  // 1. downcast inputs to bf16
  cvt6<<<dim3(36884), 256, 0, stream>>>(x, wq, wk, wv, wo, prompt,
                                        xb, wqb, wkb, wvb, wob, pb);
  // 2. QKV (+prompt K/V rows): 9 m-tiles x 16 n-tiles per z
  gemm_bt<64, false><<<dim3(144, 1, 3), 512, 0, stream>>>(
      xb, pb, wqb, wkb, wvb, q_ws, k_ws, v_ws, pk_ws, pv_ws, (float*)0, 2048, 2058);
  // 3. RoPE(q,k) + V->VT, one launch
  prep_qkv<<<dim3(2048, 3), 256, 0, stream>>>(q_ws, k_ws, fcos, fsin, v_ws, vT_ws);
  // 4. flash attention + gated prompt attention (bf16 out into v_ws)
  flash_attn<<<dim3(16, 64), 256, 0, stream>>>(
      q_ws, k_ws, vT_ws, pk_ws, pv_ws, gate, attn_ws);
  // 5. output projection: 256x128 tiles, 256 blocks (1 balanced round), f32 out
  gemm_n128<<<dim3(256), 512, 0, stream>>>(attn_ws, wob, out);
}

// Round 10
// 482.817 us; speedup vs baseline: 1.1866x; 1.0528x over previous
//
#include <hip/hip_runtime.h>
#include <hip/hip_bf16.h>
#include <stdint.h>

typedef __hip_bfloat16 bf16;
typedef __attribute__((ext_vector_type(8))) short short8;
typedef __attribute__((ext_vector_type(4))) float f32x4;

#define SCALE_ 0.08838834764831845f  // 1/sqrt(128)

static __device__ __forceinline__ float bf2f(short u) {
  unsigned int x = ((unsigned int)(unsigned short)u) << 16;
  return __builtin_bit_cast(float, x);
}
static __device__ __forceinline__ short f2bf(float f) {
  __hip_bfloat16 h = __float2bfloat16(f);
  return __builtin_bit_cast(short, h);
}
static __device__ __forceinline__ f32x4 mfma16(short8 a, short8 b, f32x4 c) {
  return __builtin_amdgcn_mfma_f32_16x16x32_bf16(a, b, c, 0, 0, 0);
}
static __device__ __forceinline__ void gl_lds16(const bf16* g, bf16* l) {
  __builtin_amdgcn_global_load_lds(
      (const __attribute__((address_space(1))) unsigned int*)g,
      (__attribute__((address_space(3))) unsigned int*)l, 16, 0, 0);
}

// ---------------------------------------------------------------------------
// f32 -> bf16 conversion for x, wq, wk, wv, wo, prompt (one fused launch).
// ---------------------------------------------------------------------------
__global__ __launch_bounds__(256) void cvt6(
    const float* __restrict__ sx, const float* __restrict__ sq,
    const float* __restrict__ sk, const float* __restrict__ sv,
    const float* __restrict__ so, const float* __restrict__ sp,
    bf16* __restrict__ dx, bf16* __restrict__ dq, bf16* __restrict__ dk,
    bf16* __restrict__ dv, bf16* __restrict__ d4, bf16* __restrict__ dp)
{
  int b = blockIdx.x;
  const float* s; bf16* d; int off;
  if (b < 4096)       { s = sx; d = dx; off = b; }
  else if (b < 12288) { s = sq; d = dq; off = b - 4096; }
  else if (b < 20480) { s = sk; d = dk; off = b - 12288; }
  else if (b < 28672) { s = sv; d = dv; off = b - 20480; }
  else if (b < 36864) { s = so; d = d4; off = b - 28672; }
  else                { s = sp; d = dp; off = b - 36864; }
  long base = (long)off * 2048 + threadIdx.x * 8;
  f32x4 a = *(const f32x4*)(s + base);
  f32x4 c = *(const f32x4*)(s + base + 4);
  short8 o;
#pragma unroll
  for (int j = 0; j < 4; j++) { o[j] = f2bf(a[j]); o[4 + j] = f2bf(c[j]); }
  *(short8*)(d + base) = o;
}

// ---------------------------------------------------------------------------
// QKV GEMM (round-6/8/9 verified structure, unchanged):
// 256x256 tile, BK=64, 8 waves (2m x 4n), 8-phase DEPTH-6, vmcnt(8) @ p0/p2.
// ---------------------------------------------------------------------------
template <int NKT, bool KSPLIT>
__global__ __launch_bounds__(512, 2) void gemm_bt(
    const bf16* __restrict__ A, const bf16* __restrict__ A2,
    const bf16* __restrict__ B0, const bf16* __restrict__ B1, const bf16* __restrict__ B2w,
    bf16* __restrict__ C0, bf16* __restrict__ C1, bf16* __restrict__ C2,
    bf16* __restrict__ P1, bf16* __restrict__ P2,
    float* __restrict__ CF,
    int M1, int Mtot)
{
  __shared__ char lds[131072];   // 8 slots x 16KB
  const int tid = threadIdx.x, w = tid >> 6, l = tid & 63;
  const int lr = l & 15, lg = l >> 4;
  const int wm = w >> 2, wn = w & 3;
  const int z = blockIdx.z;
  const bf16* Bw = KSPLIT ? B0 : ((z == 0) ? B0 : ((z == 1) ? B1 : B2w));
  bf16* C  = (z == 0) ? C0 : ((z == 1) ? C1 : C2);
  bf16* Cp = (KSPLIT || z == 0) ? (bf16*)0 : ((z == 1) ? P1 : P2);
  float* CFz = CF;
  long koff = 0;
  if (KSPLIT) { koff = (long)z * NKT * 64; CFz = CF + (long)z * M1 * 4096; }

  const int cpx = gridDim.x >> 3, orig = blockIdx.x;
  const int wg = (orig & 7) * cpx + (orig >> 3);
  const long m0 = (long)(wg >> 4) * 256;
  const long n0 = (long)(wg & 15) * 256;

  const int r0 = ((tid >> 3) << 1) | ((tid >> 2) & 1);
  const int c0 = (tid & 3) ^ ((tid >> 3) & 3);
  const bf16 *pa0, *pa1;
  {
    long mx = (long)(Mtot - M1) - 1;
    long g0 = m0 + r0, g1 = m0 + r0 + 128;
    const bf16 *q0, *q1;
    if (g0 < M1) q0 = A + g0 * 4096;
    else { long rr = g0 - M1; if (rr > mx) rr = mx; q0 = A2 + rr * 4096; }
    if (g1 < M1) q1 = A + g1 * 4096;
    else { long rr = g1 - M1; if (rr > mx) rr = mx; q1 = A2 + rr * 4096; }
    pa0 = q0 + c0 * 8 + koff;
    pa1 = q1 + c0 * 8 + koff;
  }
  const bf16* pb0 = Bw + (n0 + r0) * 4096 + c0 * 8 + koff;
  const bf16* pb1 = pb0 + (long)128 * 4096;

  const int ro  = (lr >> 1) * 128 + (((lr & 1) * 4) + (lg ^ ((lr >> 1) & 3))) * 16;
  const int aro = wm * 8192 + ro;
  const int bro = wn * 4096 + ro;

  f32x4 acc[8][4];
#pragma unroll
  for (int i = 0; i < 8; i++)
#pragma unroll
    for (int j = 0; j < 4; j++) acc[i][j] = (f32x4){0.f, 0.f, 0.f, 0.f};

  short8 af[4], bf[4];

#define STGA(S_, KE_)                                                        \
  {                                                                          \
    bf16* d_ = (bf16*)(lds + (S_) * 16384) + tid * 8;                        \
    gl_lds16(pa0 + (KE_), d_);                                               \
    gl_lds16(pa1 + (KE_), d_ + 4096);                                        \
  }
#define STGB(S_, KE_)                                                        \
  {                                                                          \
    bf16* d_ = (bf16*)(lds + (S_) * 16384) + tid * 8;                        \
    gl_lds16(pb0 + (KE_), d_);                                               \
    gl_lds16(pb1 + (KE_), d_ + 4096);                                        \
  }
#define SYNC(VM_)                                                            \
  {                                                                          \
    asm volatile("s_waitcnt vmcnt(" VM_ ")" ::: "memory");                   \
    __builtin_amdgcn_s_barrier();                                            \
    __builtin_amdgcn_sched_barrier(0);                                       \
  }
#define PHASE(PRB_, AU_, BU_, MO_, LB_, STG_)                                \
  {                                                                          \
    STG_                                                                     \
    const char* ab_ = lds + (PRB_) + (AU_) + aro;                            \
    _Pragma("unroll") for (int mi = 0; mi < 4; mi++)                         \
      af[mi] = *(const short8*)(ab_ + ((MO_) + mi) * 1024);                  \
    if (LB_) {                                                               \
      const char* bb_ = lds + (PRB_) + (BU_) + bro;                          \
      _Pragma("unroll") for (int ni = 0; ni < 4; ni++)                       \
        bf[ni] = *(const short8*)(bb_ + ni * 1024);                          \
    }                                                                        \
    asm volatile("s_waitcnt lgkmcnt(0)" ::: "memory");                       \
    __builtin_amdgcn_sched_barrier(0);                                       \
    __builtin_amdgcn_s_setprio(1);                                           \
    _Pragma("unroll") for (int mi = 0; mi < 4; mi++)                         \
      _Pragma("unroll") for (int ni = 0; ni < 4; ni++)                       \
        acc[(MO_) + mi][ni] = mfma16(af[mi], bf[ni], acc[(MO_) + mi][ni]);   \
    __builtin_amdgcn_s_setprio(0);                                           \
  }
#define KT(PRB_, S6_, S7_, S8_, S9_, KE1_, KE2_)                             \
  SYNC("8") PHASE(PRB_, 0, 16384, 0, 1, STGA(S6_, KE1_))                     \
  PHASE(PRB_, 0, 16384, 4, 0, STGB(S7_, KE1_))                               \
  SYNC("8") PHASE(PRB_, 32768, 49152, 0, 1, STGA(S8_, KE2_))                 \
  PHASE(PRB_, 32768, 49152, 4, 0, STGB(S9_, KE2_))

  STGA(0, 0) STGB(1, 0) STGA(2, 32) STGB(3, 32) STGA(4, 64) STGB(5, 64)

  for (int t = 0; t < NKT - 2; t += 2) {
    const int ka = (t + 1) * 64 + 32, kb = (t + 2) * 64;
    const int kc = (t + 2) * 64 + 32, kd = (t + 3) * 64;
    KT(0, 6, 7, 0, 1, ka, kb)
    KT(65536, 2, 3, 4, 5, kc, kd)
  }
  {
    const int kel = (NKT - 1) * 64 + 32;
    SYNC("8") PHASE(0, 0, 16384, 0, 1, STGA(6, kel))
    PHASE(0, 0, 16384, 4, 0, STGB(7, kel))
    SYNC("8") PHASE(0, 32768, 49152, 0, 1, )
    PHASE(0, 32768, 49152, 4, 0, )
  }
  SYNC("4") PHASE(65536, 0, 16384, 0, 1, )
  PHASE(65536, 0, 16384, 4, 0, )
  SYNC("0") PHASE(65536, 32768, 49152, 0, 1, )
  PHASE(65536, 32768, 49152, 4, 0, )

#undef KT
#undef PHASE
#undef SYNC
#undef STGB
#undef STGA

#pragma unroll
  for (int mi = 0; mi < 8; mi++) {
#pragma unroll
    for (int ni = 0; ni < 4; ni++) {
      long col = n0 + wn * 64 + ni * 16 + lr;
      f32x4 v = acc[mi][ni];
#pragma unroll
      for (int j = 0; j < 4; j++) {
        long row = m0 + wm * 128 + mi * 16 + lg * 4 + j;
        if (CFz) {
          CFz[row * 4096 + col] = v[j];
        } else if (row < M1) {
          *(short*)(C + row * 4096 + col) = f2bf(v[j]);
        } else if (Cp != 0 && row < Mtot) {
          *(short*)(Cp + (row - M1) * 4096 + col) = f2bf(v[j]);
        }
      }
    }
  }
}

// ---------------------------------------------------------------------------
// Out-projection GEMM (round-9 verified, unchanged): 256x128, 256 blocks.
// ---------------------------------------------------------------------------
__global__ __launch_bounds__(512, 2) void gemm_n128(
    const bf16* __restrict__ A, const bf16* __restrict__ Bw,
    float* __restrict__ CF)
{
  __shared__ char lds[98304];
  const int tid = threadIdx.x, w = tid >> 6, l = tid & 63;
  const int lr = l & 15, lg = l >> 4;
  const int wm = w >> 1, wn = w & 1;

  const int cpx = gridDim.x >> 3, orig = blockIdx.x;
  const int wg = (orig & 7) * cpx + (orig >> 3);
  const long m0 = (long)(wg >> 5) * 256;
  const long n0 = (long)(wg & 31) * 128;

  const int r0 = ((tid >> 3) << 1) | ((tid >> 2) & 1);
  const int c0 = (tid & 3) ^ ((tid >> 3) & 3);
  const bf16* pa0 = A + (m0 + r0) * 4096 + c0 * 8;
  const bf16* pa1 = pa0 + (long)128 * 4096;
  const bf16* pb0 = Bw + (n0 + r0) * 4096 + c0 * 8;

  const int ro  = (lr >> 1) * 128 + (((lr & 1) * 4) + (lg ^ ((lr >> 1) & 3))) * 16;
  const int aro = wm * 4096 + ro;
  const int bro = wn * 4096 + ro;

  f32x4 acc[4][4];
#pragma unroll
  for (int i = 0; i < 4; i++)
#pragma unroll
    for (int j = 0; j < 4; j++) acc[i][j] = (f32x4){0.f, 0.f, 0.f, 0.f};

  short8 af[4], bf[4];

#define NSTGA(SB_, KE_)                                                      \
  {                                                                          \
    bf16* d_ = (bf16*)(lds + (SB_)) + tid * 8;                               \
    gl_lds16(pa0 + (KE_), d_);                                               \
    gl_lds16(pa1 + (KE_), d_ + 4096);                                        \
  }
#define NSTGB(SB_, KE_)                                                      \
  {                                                                          \
    bf16* d_ = (bf16*)(lds + (SB_)) + tid * 8;                               \
    gl_lds16(pb0 + (KE_), d_);                                               \
  }
#define NSYNC(VM_)                                                           \
  {                                                                          \
    asm volatile("s_waitcnt vmcnt(" VM_ ")" ::: "memory");                   \
    __builtin_amdgcn_s_barrier();                                            \
    __builtin_amdgcn_sched_barrier(0);                                       \
  }
#define NPH(PRB_, AO_, BO_, STG_)                                            \
  {                                                                          \
    STG_                                                                     \
    const char* ab_ = lds + (PRB_) + (AO_) + aro;                            \
    _Pragma("unroll") for (int mi = 0; mi < 4; mi++)                         \
      af[mi] = *(const short8*)(ab_ + mi * 1024);                            \
    const char* bb_ = lds + (PRB_) + (BO_) + bro;                            \
    _Pragma("unroll") for (int ni = 0; ni < 4; ni++)                         \
      bf[ni] = *(const short8*)(bb_ + ni * 1024);                            \
    asm volatile("s_waitcnt lgkmcnt(0)" ::: "memory");                       \
    __builtin_amdgcn_sched_barrier(0);                                       \
    __builtin_amdgcn_s_setprio(1);                                           \
    _Pragma("unroll") for (int mi = 0; mi < 4; mi++)                         \
      _Pragma("unroll") for (int ni = 0; ni < 4; ni++)                       \
        acc[mi][ni] = mfma16(af[mi], bf[ni], acc[mi][ni]);                   \
    __builtin_amdgcn_s_setprio(0);                                           \
  }

  NSTGA(0, 0)      NSTGB(16384, 0)
  NSTGA(24576, 32) NSTGB(40960, 32)
  NSTGA(49152, 64) NSTGB(65536, 64)

  for (int t = 0; t < 62; t += 2) {
    const int ka = (t + 1) * 64 + 32;
    const int kb = (t + 2) * 64;
    NSYNC("3") NPH(0, 0, 16384,     NSTGA(49152 + 24576, ka) NSTGB(49152 + 40960, ka))
    NSYNC("3") NPH(0, 24576, 40960, NSTGA(0, kb) NSTGB(16384, kb))
    const int kc = (t + 2) * 64 + 32;
    const int kd = (t + 3) * 64;
    NSYNC("3") NPH(49152, 0, 16384,     NSTGA(24576, kc) NSTGB(40960, kc))
    NSYNC("3") NPH(49152, 24576, 40960, NSTGA(49152, kd) NSTGB(49152 + 16384, kd))
  }
  NSYNC("3") NPH(0, 0, 16384,     NSTGA(49152 + 24576, 63 * 64 + 32) NSTGB(49152 + 40960, 63 * 64 + 32))
  NSYNC("3") NPH(0, 24576, 40960, )
  NSYNC("3") NPH(49152, 0, 16384, )
  NSYNC("0") NPH(49152, 24576, 40960, )

#undef NPH
#undef NSYNC
#undef NSTGB
#undef NSTGA

#pragma unroll
  for (int mi = 0; mi < 4; mi++) {
#pragma unroll
    for (int ni = 0; ni < 4; ni++) {
      long col = n0 + wn * 64 + ni * 16 + lr;
      f32x4 v = acc[mi][ni];
#pragma unroll
      for (int j = 0; j < 4; j++) {
        long row = m0 + wm * 64 + mi * 16 + lg * 4 + j;
        CF[row * 4096 + col] = v[j];
      }
    }
  }
}

// ---------------------------------------------------------------------------
// Merged RoPE (q,k) + V transpose: grid (2048, 3). (round-9, unchanged)
// ---------------------------------------------------------------------------
__global__ __launch_bounds__(256) void prep_qkv(
    bf16* __restrict__ Q, bf16* __restrict__ Kb,
    const float* __restrict__ FC, const float* __restrict__ FS,
    const bf16* __restrict__ V, bf16* __restrict__ VT)
{
  const int t = threadIdx.x;
  if (blockIdx.y < 2) {
    const int row = blockIdx.x;
    const int s = row & 1023;
    bf16* base = (blockIdx.y ? Kb : Q) + (long)row * 4096 + t * 16;
    short8 v0 = *(const short8*)base;
    short8 v1 = *(const short8*)(base + 8);
    const float* cp = FC + s * 64 + (t & 7) * 8;
    const float* sp = FS + s * 64 + (t & 7) * 8;
    f32x4 c0 = *(const f32x4*)cp;
    f32x4 c1 = *(const f32x4*)(cp + 4);
    f32x4 s0 = *(const f32x4*)sp;
    f32x4 s1 = *(const f32x4*)(sp + 4);
    short8 o0, o1;
#pragma unroll
    for (int j = 0; j < 4; j++) {
      float c = c0[j], sn = s0[j];
      float e = bf2f(v0[2 * j]), od = bf2f(v0[2 * j + 1]);
      o0[2 * j] = f2bf(e * c - od * sn);
      o0[2 * j + 1] = f2bf(e * sn + od * c);
      float c2 = c1[j], sn2 = s1[j];
      float e2 = bf2f(v1[2 * j]), od2 = bf2f(v1[2 * j + 1]);
      o1[2 * j] = f2bf(e2 * c2 - od2 * sn2);
      o1[2 * j + 1] = f2bf(e2 * sn2 + od2 * c2);
    }
    *(short8*)base = o0;
    *(short8*)(base + 8) = o1;
    return;
  }
  if (blockIdx.x >= 1024) return;
  __shared__ bf16 T[64 * 128];
  const int st = (blockIdx.x & 15) * 64, bh = blockIdx.x >> 4;
  const int b = bh >> 5, h = bh & 31;
  const bf16* src = V + ((long)(b * 1024 + st)) * 4096 + h * 128;
#pragma unroll
  for (int rr = 0; rr < 4; ++rr) {
    int i = t + rr * 256;
    int s_l = i >> 4, c = i & 15;
    short8 v = *(const short8*)(src + (long)s_l * 4096 + c * 8);
    *(short8*)((char*)T + s_l * 256 + ((c ^ (s_l & 7)) * 16)) = v;
  }
  __syncthreads();
#pragma unroll
  for (int rr = 0; rr < 4; ++rr) {
    int i = t + rr * 256;
    int d = i >> 3, cs = i & 7;
    short8 ov;
#pragma unroll
    for (int e = 0; e < 8; e++) {
      int s_l = cs * 8 + e;
      ov[e] = *(const short*)((char*)T + s_l * 256 + (((d >> 3) ^ (s_l & 7)) * 16) + (d & 7) * 2);
    }
    *(short8*)(VT + ((long)bh * 128 + d) * 1024 + st + cs * 8) = ov;
  }
}

// ---------------------------------------------------------------------------
// Flash attention v2: KVBLK=64, double-buffered K/V with counted vmcnt(8),
// two raw s_barriers per 64 keys, swizzled P buffer, 80KB LDS -> 2 blocks/CU.
// Pipeline: iter j: [barrier: all waves done reading buf[(j+1)&1] from iter
// j-1] -> stage tile j+1 into buf[(j+1)&1] (8 gl_lds/wave) -> vmcnt(8)
// certifies tile j's 8 oldest loads -> [barrier: collective visibility] ->
// compute tile j. Last iter drains vmcnt(0). Per-wave P round-trip uses
// lgkmcnt(0)+sched_barrier (same-wave only). PKl/PVl staged once; their
// ds_writes complete before the first in-loop lgkmcnt(0), and reads happen
// after >=1 subsequent barrier.
// K LDS [64][128]: row*256B, chunk XOR (row&7). V LDS [128][64]: d*128B,
// chunk XOR (d&7). P LDS [16][128B]: chunk XOR (row&7) (bank fix: naive
// 128B-stride read was a 16-way conflict).
// ---------------------------------------------------------------------------
__global__ __launch_bounds__(256) void flash_attn(
    const bf16* __restrict__ Q, const bf16* __restrict__ Kg, const bf16* __restrict__ VT,
    const bf16* __restrict__ PK, const bf16* __restrict__ PV,
    const float* __restrict__ GATE, bf16* __restrict__ O)
{
  __shared__ bf16 Kl[2][64 * 128];
  __shared__ bf16 Vl[2][128 * 64];
  __shared__ bf16 PKl[16 * 128];
  __shared__ bf16 PVl[128 * 16];
  __shared__ bf16 Pl[4][16 * 64];
  const int tid = threadIdx.x, w = tid >> 6, l = tid & 63;
  const int lg = l >> 4, lr = l & 15;
  const int qb = blockIdx.x, bh = blockIdx.y;
  const int b = bh >> 5, h = bh & 31;
  const int q0 = qb * 64 + w * 16;

  short8 qf[4];
  {
    const bf16* qp = Q + ((long)(b * 1024 + q0 + lr)) * 4096 + h * 128 + lg * 8;
#pragma unroll
    for (int c = 0; c < 4; c++) qf[c] = *(const short8*)(qp + c * 32);
  }
  {
    int rowp = tid >> 4, pc = tid & 15, lc = pc ^ (rowp & 7);
    short8 v = {0, 0, 0, 0, 0, 0, 0, 0};
    if (rowp < 10) v = *(const short8*)(PK + (long)rowp * 4096 + h * 128 + lc * 8);
    *(short8*)((char*)PKl + tid * 16) = v;
  }
  {
    int d = tid >> 1, pb = (tid & 1) * 8;
#pragma unroll
    for (int e = 0; e < 8; e++) {
      int p = pb + e;
      short v = 0;
      if (p < 10) v = __builtin_bit_cast(short, PV[(long)p * 4096 + h * 128 + d]);
      *(short*)((char*)PVl + d * 32 + (((p >> 3) ^ (d & 1)) * 16) + (p & 7) * 2) = v;
    }
  }
  const float gate = GATE[h];

  f32x4 o[8];
#pragma unroll
  for (int i = 0; i < 8; i++) o[i] = (f32x4){0.f, 0.f, 0.f, 0.f};
  float m_[4] = {-1e30f, -1e30f, -1e30f, -1e30f};
  float l_[4] = {0.f, 0.f, 0.f, 0.f};

  const int nt = qb + 1;   // 64-key tiles
  const bf16* Kbase = Kg + ((long)b * 1024) * 4096 + h * 128;
  const bf16* Vbase = VT + ((long)bh) * 128 * 1024;
  bf16* pw = &Pl[w][0];

  // per-thread staging: 4 K-chunks + 4 V-chunks per tile (8 gl_lds/wave)
#define FSTG(BUF_, J_)                                                        \
  {                                                                           \
    _Pragma("unroll") for (int r_ = 0; r_ < 4; ++r_) {                        \
      int i_ = tid + 256 * r_;                                                \
      int kr_ = i_ >> 4, kc_ = (i_ & 15) ^ (kr_ & 7);                         \
      gl_lds16(Kbase + (long)((J_) * 64 + kr_) * 4096 + kc_ * 8,              \
               &Kl[BUF_][0] + i_ * 8);                                        \
      int vd_ = i_ >> 3, vc_ = (i_ & 7) ^ (vd_ & 7);                          \
      gl_lds16(Vbase + (long)vd_ * 1024 + (J_) * 64 + vc_ * 8,                \
               &Vl[BUF_][0] + i_ * 8);                                        \
    }                                                                         \
  }

  FSTG(0, 0)
  for (int j = 0; j < nt; ++j) {
    __builtin_amdgcn_s_barrier();          // buf[(j+1)&1] readers (iter j-1) done
    if (j + 1 < nt) {
      FSTG((j + 1) & 1, j + 1)
      asm volatile("s_waitcnt vmcnt(8)" ::: "memory");
    } else {
      asm volatile("s_waitcnt vmcnt(0)" ::: "memory");
    }
    __builtin_amdgcn_s_barrier();          // tile j collectively visible
    __builtin_amdgcn_sched_barrier(0);

    const char* kb = (const char*)&Kl[j & 1][0];
    const char* vb = (const char*)&Vl[j & 1][0];

    // scores: 4 x 16-key strips
    f32x4 s[4];
#pragma unroll
    for (int ns = 0; ns < 4; ns++) {
      f32x4 a = (f32x4){0.f, 0.f, 0.f, 0.f};
      int krow = ns * 16 + lr;
      int sw = krow & 7;
#pragma unroll
      for (int c = 0; c < 4; c++) {
        short8 kf = *(const short8*)(kb + krow * 256 + (((c * 4 + lg) ^ sw) * 16));
        a = mfma16(qf[c], kf, a);
      }
      int key = j * 64 + krow;
#pragma unroll
      for (int r = 0; r < 4; r++) {
        int qr = q0 + lg * 4 + r;
        s[ns][r] = a[r] * SCALE_ + ((key <= qr) ? 0.0f : -1e30f);
      }
    }
    // online softmax over 64 keys (one rescale per tile)
    float mx[4], cor[4], sum[4];
#pragma unroll
    for (int r = 0; r < 4; r++)
      mx[r] = fmaxf(fmaxf(s[0][r], s[1][r]), fmaxf(s[2][r], s[3][r]));
#pragma unroll
    for (int xm = 1; xm < 16; xm <<= 1)
#pragma unroll
      for (int r = 0; r < 4; r++) mx[r] = fmaxf(mx[r], __shfl_xor(mx[r], xm, 64));
#pragma unroll
    for (int r = 0; r < 4; r++) {
      float mn = fmaxf(m_[r], mx[r]);
      cor[r] = __expf(m_[r] - mn);
      m_[r] = mn;
      sum[r] = 0.f;
    }
#pragma unroll
    for (int ns = 0; ns < 4; ns++)
#pragma unroll
      for (int r = 0; r < 4; r++) {
        s[ns][r] = __expf(s[ns][r] - m_[r]);
        sum[r] += s[ns][r];
      }
#pragma unroll
    for (int xm = 1; xm < 16; xm <<= 1)
#pragma unroll
      for (int r = 0; r < 4; r++) sum[r] += __shfl_xor(sum[r], xm, 64);
#pragma unroll
    for (int r = 0; r < 4; r++) l_[r] = l_[r] * cor[r] + sum[r];
#pragma unroll
    for (int df = 0; df < 8; df++)
#pragma unroll
      for (int r = 0; r < 4; r++) o[df][r] *= cor[r];

    // P (C-layout) -> per-wave swizzled LDS -> A-frags
#pragma unroll
    for (int ns = 0; ns < 4; ns++)
#pragma unroll
      for (int r = 0; r < 4; r++) {
        int row = lg * 4 + r;
        int ch = ns * 2 + (lr >> 3);
        *(short*)((char*)pw + row * 128 + ((ch ^ (row & 7)) * 16) + (lr & 7) * 2)
            = f2bf(s[ns][r]);
      }
    asm volatile("s_waitcnt lgkmcnt(0)" ::: "memory");
    __builtin_amdgcn_sched_barrier(0);
    short8 pf0 = *(const short8*)((char*)pw + lr * 128 + ((lg ^ (lr & 7)) * 16));
    short8 pf1 = *(const short8*)((char*)pw + lr * 128 + (((4 + lg) ^ (lr & 7)) * 16));

    // PV: 8 d-frags x 2 k-slots
#pragma unroll
    for (int df = 0; df < 8; df++) {
      int d = df * 16 + lr;
      short8 vf0 = *(const short8*)(vb + d * 128 + ((lg ^ (d & 7)) * 16));
      short8 vf1 = *(const short8*)(vb + d * 128 + (((4 + lg) ^ (d & 7)) * 16));
      o[df] = mfma16(pf0, vf0, o[df]);
      o[df] = mfma16(pf1, vf1, o[df]);
    }
  }
#undef FSTG

  // ---- prompt attention (separate softmax, gated) ----
  f32x4 ps;
  {
    f32x4 a = (f32x4){0.f, 0.f, 0.f, 0.f};
    const char* kp = (const char*)PKl + lr * 256;
    int sw = lr & 7;
#pragma unroll
    for (int c = 0; c < 4; c++) {
      short8 kf = *(const short8*)(kp + (((c * 4 + lg) ^ sw) * 16));
      a = mfma16(qf[c], kf, a);
    }
#pragma unroll
    for (int r = 0; r < 4; r++) ps[r] = (lr < 10) ? a[r] * SCALE_ : -1e30f;
  }
  {
    float pm[4], pss[4];
#pragma unroll
    for (int r = 0; r < 4; r++) pm[r] = ps[r];
#pragma unroll
    for (int xm = 1; xm < 16; xm <<= 1)
#pragma unroll
      for (int r = 0; r < 4; r++) pm[r] = fmaxf(pm[r], __shfl_xor(pm[r], xm, 64));
#pragma unroll
    for (int r = 0; r < 4; r++) { ps[r] = __expf(ps[r] - pm[r]); pss[r] = ps[r]; }
#pragma unroll
    for (int xm = 1; xm < 16; xm <<= 1)
#pragma unroll
      for (int r = 0; r < 4; r++) pss[r] += __shfl_xor(pss[r], xm, 64);
#pragma unroll
    for (int r = 0; r < 4; r++) ps[r] = ps[r] / pss[r];
  }
  // write prompt-P (keys 0..15 = ps, keys 16..31 = 0) in the swizzled layout
#pragma unroll
  for (int r = 0; r < 4; r++) {
    int row = lg * 4 + r;
    int ch0 = (lr >> 3);
    *(short*)((char*)pw + row * 128 + ((ch0 ^ (row & 7)) * 16) + (lr & 7) * 2) = f2bf(ps[r]);
    int ch1 = 2 + (lr >> 3);
    *(short*)((char*)pw + row * 128 + ((ch1 ^ (row & 7)) * 16) + (lr & 7) * 2) = 0;
  }
  asm volatile("s_waitcnt lgkmcnt(0)" ::: "memory");
  __builtin_amdgcn_sched_barrier(0);
  short8 pf2 = *(const short8*)((char*)pw + lr * 128 + ((lg ^ (lr & 7)) * 16));
  f32x4 po[8];
#pragma unroll
  for (int df = 0; df < 8; df++) {
    int d = df * 16 + lr;
    short8 vf = {0, 0, 0, 0, 0, 0, 0, 0};
    if (lg < 2) vf = *(const short8*)((const char*)PVl + d * 32 + ((lg ^ (d & 1)) * 16));
    po[df] = mfma16(pf2, vf, (f32x4){0.f, 0.f, 0.f, 0.f});
  }

  bf16* op = O + ((long)(b * 1024 + q0 + lg * 4)) * 4096 + h * 128 + lr;
#pragma unroll
  for (int df = 0; df < 8; df++)
#pragma unroll
    for (int r = 0; r < 4; r++) {
      float val = o[df][r] / l_[r] + gate * po[df][r];
      *(short*)(op + (long)r * 4096 + df * 16) = f2bf(val);
    }
}

// ---------------------------------------------------------------------------
extern "C" void kernel_launch(void* const* d_in, const int* in_sizes, int n_in,
                              void* d_out, int out_size, void* d_ws, size_t ws_size,
                              hipStream_t stream) {
  (void)in_sizes; (void)n_in; (void)out_size; (void)ws_size;
  const float* x      = (const float*)d_in[0];
  const float* wq     = (const float*)d_in[1];
  const float* wk     = (const float*)d_in[2];
  const float* wv     = (const float*)d_in[3];
  const float* wo     = (const float*)d_in[4];
  const float* prompt = (const float*)d_in[5];
  const float* gate   = (const float*)d_in[6];
  const float* fcos   = (const float*)d_in[7];
  const float* fsin   = (const float*)d_in[8];
  float* out = (float*)d_out;
  char* ws = (char*)d_ws;

  size_t o = 0;
  bf16* xb  = (bf16*)(ws + o); o += (size_t)8388608 * 2;
  bf16* wqb = (bf16*)(ws + o); o += (size_t)16777216 * 2;
  bf16* wkb = (bf16*)(ws + o); o += (size_t)16777216 * 2;
  bf16* wvb = (bf16*)(ws + o); o += (size_t)16777216 * 2;
  bf16* wob = (bf16*)(ws + o); o += (size_t)16777216 * 2;
  bf16* pb  = (bf16*)(ws + o); o += (size_t)40960 * 2;
  bf16* q_ws  = (bf16*)(ws + o); o += (size_t)2048 * 4096 * 2;
  bf16* k_ws  = (bf16*)(ws + o); o += (size_t)2048 * 4096 * 2;
  bf16* v_ws  = (bf16*)(ws + o); o += (size_t)2048 * 4096 * 2;
  bf16* vT_ws = (bf16*)(ws + o); o += (size_t)2048 * 4096 * 2;
  bf16* pk_ws = (bf16*)(ws + o); o += (size_t)40960 * 2;
  bf16* pv_ws = (bf16*)(ws + o); o += (size_t)40960 * 2;
  bf16* attn_ws = v_ws;

  // 1. downcast inputs to bf16
  cvt6<<<dim3(36884), 256, 0, stream>>>(x, wq, wk, wv, wo, prompt,
                                        xb, wqb, wkb, wvb, wob, pb);
  // 2. QKV (+prompt K/V rows): 9 m-tiles x 16 n-tiles per z
  gemm_bt<64, false><<<dim3(144, 1, 3), 512, 0, stream>>>(
      xb, pb, wqb, wkb, wvb, q_ws, k_ws, v_ws, pk_ws, pv_ws, (float*)0, 2048, 2058);
  // 3. RoPE(q,k) + V->VT, one launch
  prep_qkv<<<dim3(2048, 3), 256, 0, stream>>>(q_ws, k_ws, fcos, fsin, v_ws, vT_ws);
  // 4. flash attention v2 (KVBLK=64, dbuf, counted vmcnt)
  flash_attn<<<dim3(16, 64), 256, 0, stream>>>(
      q_ws, k_ws, vT_ws, pk_ws, pv_ws, gate, attn_ws);
  // 5. output projection: 256x128 tiles, 256 blocks, f32 out
  gemm_n128<<<dim3(256), 512, 0, stream>>>(attn_ws, wob, out);
}

// Round 12
// 477.463 us; speedup vs baseline: 1.1999x; 1.0112x over previous
//
#include <hip/hip_runtime.h>
#include <hip/hip_bf16.h>
#include <stdint.h>

typedef __hip_bfloat16 bf16;
typedef __attribute__((ext_vector_type(8))) short short8;
typedef __attribute__((ext_vector_type(4))) float f32x4;

#define SCALE_ 0.08838834764831845f  // 1/sqrt(128)

static __device__ __forceinline__ float bf2f(short u) {
  unsigned int x = ((unsigned int)(unsigned short)u) << 16;
  return __builtin_bit_cast(float, x);
}
static __device__ __forceinline__ short f2bf(float f) {
  __hip_bfloat16 h = __float2bfloat16(f);
  return __builtin_bit_cast(short, h);
}
static __device__ __forceinline__ f32x4 mfma16(short8 a, short8 b, f32x4 c) {
  return __builtin_amdgcn_mfma_f32_16x16x32_bf16(a, b, c, 0, 0, 0);
}
static __device__ __forceinline__ void gl_lds16(const bf16* g, bf16* l) {
  __builtin_amdgcn_global_load_lds(
      (const __attribute__((address_space(1))) unsigned int*)g,
      (__attribute__((address_space(3))) unsigned int*)l, 16, 0, 0);
}

// ---------------------------------------------------------------------------
// f32 -> bf16 conversion for x, wq, wk, wv, wo, prompt (one fused launch).
// ---------------------------------------------------------------------------
__global__ __launch_bounds__(256) void cvt6(
    const float* __restrict__ sx, const float* __restrict__ sq,
    const float* __restrict__ sk, const float* __restrict__ sv,
    const float* __restrict__ so, const float* __restrict__ sp,
    bf16* __restrict__ dx, bf16* __restrict__ dq, bf16* __restrict__ dk,
    bf16* __restrict__ dv, bf16* __restrict__ d4, bf16* __restrict__ dp)
{
  int b = blockIdx.x;
  const float* s; bf16* d; int off;
  if (b < 4096)       { s = sx; d = dx; off = b; }
  else if (b < 12288) { s = sq; d = dq; off = b - 4096; }
  else if (b < 20480) { s = sk; d = dk; off = b - 12288; }
  else if (b < 28672) { s = sv; d = dv; off = b - 20480; }
  else if (b < 36864) { s = so; d = d4; off = b - 28672; }
  else                { s = sp; d = dp; off = b - 36864; }
  long base = (long)off * 2048 + threadIdx.x * 8;
  f32x4 a = *(const f32x4*)(s + base);
  f32x4 c = *(const f32x4*)(s + base + 4);
  short8 o;
#pragma unroll
  for (int j = 0; j < 4; j++) { o[j] = f2bf(a[j]); o[4 + j] = f2bf(c[j]); }
  *(short8*)(d + base) = o;
}

// ---------------------------------------------------------------------------
// QKV GEMM (round-6/8/9/10 verified structure, unchanged):
// 256x256 tile, BK=64, 8 waves (2m x 4n), 8-phase DEPTH-6, vmcnt(8) @ p0/p2.
// ---------------------------------------------------------------------------
template <int NKT, bool KSPLIT>
__global__ __launch_bounds__(512, 2) void gemm_bt(
    const bf16* __restrict__ A, const bf16* __restrict__ A2,
    const bf16* __restrict__ B0, const bf16* __restrict__ B1, const bf16* __restrict__ B2w,
    bf16* __restrict__ C0, bf16* __restrict__ C1, bf16* __restrict__ C2,
    bf16* __restrict__ P1, bf16* __restrict__ P2,
    float* __restrict__ CF,
    int M1, int Mtot)
{
  __shared__ char lds[131072];   // 8 slots x 16KB
  const int tid = threadIdx.x, w = tid >> 6, l = tid & 63;
  const int lr = l & 15, lg = l >> 4;
  const int wm = w >> 2, wn = w & 3;
  const int z = blockIdx.z;
  const bf16* Bw = KSPLIT ? B0 : ((z == 0) ? B0 : ((z == 1) ? B1 : B2w));
  bf16* C  = (z == 0) ? C0 : ((z == 1) ? C1 : C2);
  bf16* Cp = (KSPLIT || z == 0) ? (bf16*)0 : ((z == 1) ? P1 : P2);
  float* CFz = CF;
  long koff = 0;
  if (KSPLIT) { koff = (long)z * NKT * 64; CFz = CF + (long)z * M1 * 4096; }

  const int cpx = gridDim.x >> 3, orig = blockIdx.x;
  const int wg = (orig & 7) * cpx + (orig >> 3);
  const long m0 = (long)(wg >> 4) * 256;
  const long n0 = (long)(wg & 15) * 256;

  const int r0 = ((tid >> 3) << 1) | ((tid >> 2) & 1);
  const int c0 = (tid & 3) ^ ((tid >> 3) & 3);
  const bf16 *pa0, *pa1;
  {
    long mx = (long)(Mtot - M1) - 1;
    long g0 = m0 + r0, g1 = m0 + r0 + 128;
    const bf16 *q0, *q1;
    if (g0 < M1) q0 = A + g0 * 4096;
    else { long rr = g0 - M1; if (rr > mx) rr = mx; q0 = A2 + rr * 4096; }
    if (g1 < M1) q1 = A + g1 * 4096;
    else { long rr = g1 - M1; if (rr > mx) rr = mx; q1 = A2 + rr * 4096; }
    pa0 = q0 + c0 * 8 + koff;
    pa1 = q1 + c0 * 8 + koff;
  }
  const bf16* pb0 = Bw + (n0 + r0) * 4096 + c0 * 8 + koff;
  const bf16* pb1 = pb0 + (long)128 * 4096;

  const int ro  = (lr >> 1) * 128 + (((lr & 1) * 4) + (lg ^ ((lr >> 1) & 3))) * 16;
  const int aro = wm * 8192 + ro;
  const int bro = wn * 4096 + ro;

  f32x4 acc[8][4];
#pragma unroll
  for (int i = 0; i < 8; i++)
#pragma unroll
    for (int j = 0; j < 4; j++) acc[i][j] = (f32x4){0.f, 0.f, 0.f, 0.f};

  short8 af[4], bf[4];

#define STGA(S_, KE_)                                                        \
  {                                                                          \
    bf16* d_ = (bf16*)(lds + (S_) * 16384) + tid * 8;                        \
    gl_lds16(pa0 + (KE_), d_);                                               \
    gl_lds16(pa1 + (KE_), d_ + 4096);                                        \
  }
#define STGB(S_, KE_)                                                        \
  {                                                                          \
    bf16* d_ = (bf16*)(lds + (S_) * 16384) + tid * 8;                        \
    gl_lds16(pb0 + (KE_), d_);                                               \
    gl_lds16(pb1 + (KE_), d_ + 4096);                                        \
  }
#define SYNC(VM_)                                                            \
  {                                                                          \
    asm volatile("s_waitcnt vmcnt(" VM_ ")" ::: "memory");                   \
    __builtin_amdgcn_s_barrier();                                            \
    __builtin_amdgcn_sched_barrier(0);                                       \
  }
#define PHASE(PRB_, AU_, BU_, MO_, LB_, STG_)                                \
  {                                                                          \
    STG_                                                                     \
    const char* ab_ = lds + (PRB_) + (AU_) + aro;                            \
    _Pragma("unroll") for (int mi = 0; mi < 4; mi++)                         \
      af[mi] = *(const short8*)(ab_ + ((MO_) + mi) * 1024);                  \
    if (LB_) {                                                               \
      const char* bb_ = lds + (PRB_) + (BU_) + bro;                          \
      _Pragma("unroll") for (int ni = 0; ni < 4; ni++)                       \
        bf[ni] = *(const short8*)(bb_ + ni * 1024);                          \
    }                                                                        \
    asm volatile("s_waitcnt lgkmcnt(0)" ::: "memory");                       \
    __builtin_amdgcn_sched_barrier(0);                                       \
    __builtin_amdgcn_s_setprio(1);                                           \
    _Pragma("unroll") for (int mi = 0; mi < 4; mi++)                         \
      _Pragma("unroll") for (int ni = 0; ni < 4; ni++)                       \
        acc[(MO_) + mi][ni] = mfma16(af[mi], bf[ni], acc[(MO_) + mi][ni]);   \
    __builtin_amdgcn_s_setprio(0);                                           \
  }
#define KT(PRB_, S6_, S7_, S8_, S9_, KE1_, KE2_)                             \
  SYNC("8") PHASE(PRB_, 0, 16384, 0, 1, STGA(S6_, KE1_))                     \
  PHASE(PRB_, 0, 16384, 4, 0, STGB(S7_, KE1_))                               \
  SYNC("8") PHASE(PRB_, 32768, 49152, 0, 1, STGA(S8_, KE2_))                 \
  PHASE(PRB_, 32768, 49152, 4, 0, STGB(S9_, KE2_))

  STGA(0, 0) STGB(1, 0) STGA(2, 32) STGB(3, 32) STGA(4, 64) STGB(5, 64)

  for (int t = 0; t < NKT - 2; t += 2) {
    const int ka = (t + 1) * 64 + 32, kb = (t + 2) * 64;
    const int kc = (t + 2) * 64 + 32, kd = (t + 3) * 64;
    KT(0, 6, 7, 0, 1, ka, kb)
    KT(65536, 2, 3, 4, 5, kc, kd)
  }
  {
    const int kel = (NKT - 1) * 64 + 32;
    SYNC("8") PHASE(0, 0, 16384, 0, 1, STGA(6, kel))
    PHASE(0, 0, 16384, 4, 0, STGB(7, kel))
    SYNC("8") PHASE(0, 32768, 49152, 0, 1, )
    PHASE(0, 32768, 49152, 4, 0, )
  }
  SYNC("4") PHASE(65536, 0, 16384, 0, 1, )
  PHASE(65536, 0, 16384, 4, 0, )
  SYNC("0") PHASE(65536, 32768, 49152, 0, 1, )
  PHASE(65536, 32768, 49152, 4, 0, )

#undef KT
#undef PHASE
#undef SYNC
#undef STGB
#undef STGA

#pragma unroll
  for (int mi = 0; mi < 8; mi++) {
#pragma unroll
    for (int ni = 0; ni < 4; ni++) {
      long col = n0 + wn * 64 + ni * 16 + lr;
      f32x4 v = acc[mi][ni];
#pragma unroll
      for (int j = 0; j < 4; j++) {
        long row = m0 + wm * 128 + mi * 16 + lg * 4 + j;
        if (CFz) {
          CFz[row * 4096 + col] = v[j];
        } else if (row < M1) {
          *(short*)(C + row * 4096 + col) = f2bf(v[j]);
        } else if (Cp != 0 && row < Mtot) {
          *(short*)(Cp + (row - M1) * 4096 + col) = f2bf(v[j]);
        }
      }
    }
  }
}

// ---------------------------------------------------------------------------
// Out-projection GEMM (round-9/10 verified, unchanged): 256x128, 256 blocks.
// ---------------------------------------------------------------------------
__global__ __launch_bounds__(512, 2) void gemm_n128(
    const bf16* __restrict__ A, const bf16* __restrict__ Bw,
    float* __restrict__ CF)
{
  __shared__ char lds[98304];
  const int tid = threadIdx.x, w = tid >> 6, l = tid & 63;
  const int lr = l & 15, lg = l >> 4;
  const int wm = w >> 1, wn = w & 1;

  const int cpx = gridDim.x >> 3, orig = blockIdx.x;
  const int wg = (orig & 7) * cpx + (orig >> 3);
  const long m0 = (long)(wg >> 5) * 256;
  const long n0 = (long)(wg & 31) * 128;

  const int r0 = ((tid >> 3) << 1) | ((tid >> 2) & 1);
  const int c0 = (tid & 3) ^ ((tid >> 3) & 3);
  const bf16* pa0 = A + (m0 + r0) * 4096 + c0 * 8;
  const bf16* pa1 = pa0 + (long)128 * 4096;
  const bf16* pb0 = Bw + (n0 + r0) * 4096 + c0 * 8;

  const int ro  = (lr >> 1) * 128 + (((lr & 1) * 4) + (lg ^ ((lr >> 1) & 3))) * 16;
  const int aro = wm * 4096 + ro;
  const int bro = wn * 4096 + ro;

  f32x4 acc[4][4];
#pragma unroll
  for (int i = 0; i < 4; i++)
#pragma unroll
    for (int j = 0; j < 4; j++) acc[i][j] = (f32x4){0.f, 0.f, 0.f, 0.f};

  short8 af[4], bf[4];

#define NSTGA(SB_, KE_)                                                      \
  {                                                                          \
    bf16* d_ = (bf16*)(lds + (SB_)) + tid * 8;                               \
    gl_lds16(pa0 + (KE_), d_);                                               \
    gl_lds16(pa1 + (KE_), d_ + 4096);                                        \
  }
#define NSTGB(SB_, KE_)                                                      \
  {                                                                          \
    bf16* d_ = (bf16*)(lds + (SB_)) + tid * 8;                               \
    gl_lds16(pb0 + (KE_), d_);                                               \
  }
#define NSYNC(VM_)                                                           \
  {                                                                          \
    asm volatile("s_waitcnt vmcnt(" VM_ ")" ::: "memory");                   \
    __builtin_amdgcn_s_barrier();                                            \
    __builtin_amdgcn_sched_barrier(0);                                       \
  }
#define NPH(PRB_, AO_, BO_, STG_)                                            \
  {                                                                          \
    STG_                                                                     \
    const char* ab_ = lds + (PRB_) + (AO_) + aro;                            \
    _Pragma("unroll") for (int mi = 0; mi < 4; mi++)                         \
      af[mi] = *(const short8*)(ab_ + mi * 1024);                            \
    const char* bb_ = lds + (PRB_) + (BO_) + bro;                            \
    _Pragma("unroll") for (int ni = 0; ni < 4; ni++)                         \
      bf[ni] = *(const short8*)(bb_ + ni * 1024);                            \
    asm volatile("s_waitcnt lgkmcnt(0)" ::: "memory");                       \
    __builtin_amdgcn_sched_barrier(0);                                       \
    __builtin_amdgcn_s_setprio(1);                                           \
    _Pragma("unroll") for (int mi = 0; mi < 4; mi++)                         \
      _Pragma("unroll") for (int ni = 0; ni < 4; ni++)                       \
        acc[mi][ni] = mfma16(af[mi], bf[ni], acc[mi][ni]);                   \
    __builtin_amdgcn_s_setprio(0);                                           \
  }

  NSTGA(0, 0)      NSTGB(16384, 0)
  NSTGA(24576, 32) NSTGB(40960, 32)
  NSTGA(49152, 64) NSTGB(65536, 64)

  for (int t = 0; t < 62; t += 2) {
    const int ka = (t + 1) * 64 + 32;
    const int kb = (t + 2) * 64;
    NSYNC("3") NPH(0, 0, 16384,     NSTGA(49152 + 24576, ka) NSTGB(49152 + 40960, ka))
    NSYNC("3") NPH(0, 24576, 40960, NSTGA(0, kb) NSTGB(16384, kb))
    const int kc = (t + 2) * 64 + 32;
    const int kd = (t + 3) * 64;
    NSYNC("3") NPH(49152, 0, 16384,     NSTGA(24576, kc) NSTGB(40960, kc))
    NSYNC("3") NPH(49152, 24576, 40960, NSTGA(49152, kd) NSTGB(49152 + 16384, kd))
  }
  NSYNC("3") NPH(0, 0, 16384,     NSTGA(49152 + 24576, 63 * 64 + 32) NSTGB(49152 + 40960, 63 * 64 + 32))
  NSYNC("3") NPH(0, 24576, 40960, )
  NSYNC("3") NPH(49152, 0, 16384, )
  NSYNC("0") NPH(49152, 24576, 40960, )

#undef NPH
#undef NSYNC
#undef NSTGB
#undef NSTGA

#pragma unroll
  for (int mi = 0; mi < 4; mi++) {
#pragma unroll
    for (int ni = 0; ni < 4; ni++) {
      long col = n0 + wn * 64 + ni * 16 + lr;
      f32x4 v = acc[mi][ni];
#pragma unroll
      for (int j = 0; j < 4; j++) {
        long row = m0 + wm * 64 + mi * 16 + lg * 4 + j;
        CF[row * 4096 + col] = v[j];
      }
    }
  }
}

// ---------------------------------------------------------------------------
// Merged K-RoPE + V transpose: grid (2048, 2). (round-11, kept)
// y==0: rope row x of K (Q rope is fused into flash's Q load).
// y==1, x<1024: transpose tile (x&15, x>>4).
// ---------------------------------------------------------------------------
__global__ __launch_bounds__(256) void prep_qkv(
    bf16* __restrict__ Kb,
    const float* __restrict__ FC, const float* __restrict__ FS,
    const bf16* __restrict__ V, bf16* __restrict__ VT)
{
  const int t = threadIdx.x;
  if (blockIdx.y == 0) {
    const int row = blockIdx.x;
    const int s = row & 1023;
    bf16* base = Kb + (long)row * 4096 + t * 16;
    short8 v0 = *(const short8*)base;
    short8 v1 = *(const short8*)(base + 8);
    const float* cp = FC + s * 64 + (t & 7) * 8;
    const float* sp = FS + s * 64 + (t & 7) * 8;
    f32x4 c0 = *(const f32x4*)cp;
    f32x4 c1 = *(const f32x4*)(cp + 4);
    f32x4 s0 = *(const f32x4*)sp;
    f32x4 s1 = *(const f32x4*)(sp + 4);
    short8 o0, o1;
#pragma unroll
    for (int j = 0; j < 4; j++) {
      float c = c0[j], sn = s0[j];
      float e = bf2f(v0[2 * j]), od = bf2f(v0[2 * j + 1]);
      o0[2 * j] = f2bf(e * c - od * sn);
      o0[2 * j + 1] = f2bf(e * sn + od * c);
      float c2 = c1[j], sn2 = s1[j];
      float e2 = bf2f(v1[2 * j]), od2 = bf2f(v1[2 * j + 1]);
      o1[2 * j] = f2bf(e2 * c2 - od2 * sn2);
      o1[2 * j + 1] = f2bf(e2 * sn2 + od2 * c2);
    }
    *(short8*)base = o0;
    *(short8*)(base + 8) = o1;
    return;
  }
  if (blockIdx.x >= 1024) return;
  __shared__ bf16 T[64 * 128];
  const int st = (blockIdx.x & 15) * 64, bh = blockIdx.x >> 4;
  const int b = bh >> 5, h = bh & 31;
  const bf16* src = V + ((long)(b * 1024 + st)) * 4096 + h * 128;
#pragma unroll
  for (int rr = 0; rr < 4; ++rr) {
    int i = t + rr * 256;
    int s_l = i >> 4, c = i & 15;
    short8 v = *(const short8*)(src + (long)s_l * 4096 + c * 8);
    *(short8*)((char*)T + s_l * 256 + ((c ^ (s_l & 7)) * 16)) = v;
  }
  __syncthreads();
#pragma unroll
  for (int rr = 0; rr < 4; ++rr) {
    int i = t + rr * 256;
    int d = i >> 3, cs = i & 7;
    short8 ov;
#pragma unroll
    for (int e = 0; e < 8; e++) {
      int s_l = cs * 8 + e;
      ov[e] = *(const short*)((char*)T + s_l * 256 + (((d >> 3) ^ (s_l & 7)) * 16) + (d & 7) * 2);
    }
    *(short8*)(VT + ((long)bh * 128 + d) * 1024 + st + cs * 8) = ov;
  }
}

// ---------------------------------------------------------------------------
// Flash attention v3b: round-10 pipeline + Q-RoPE fused into the Q register
// load (bit-identical math to the old prep pass: same bf16 inputs, f32
// freqs, one f2bf round). T13 defer-max REVERTED (round-11 fail: absmax
// 0.031 -> 0.148 with THR=8; always-rescale restores verified numerics).
// ---------------------------------------------------------------------------
__global__ __launch_bounds__(256) void flash_attn(
    const bf16* __restrict__ Q, const bf16* __restrict__ Kg, const bf16* __restrict__ VT,
    const bf16* __restrict__ PK, const bf16* __restrict__ PV,
    const float* __restrict__ GATE, const float* __restrict__ FC,
    const float* __restrict__ FS, bf16* __restrict__ O)
{
  __shared__ bf16 Kl[2][64 * 128];
  __shared__ bf16 Vl[2][128 * 64];
  __shared__ bf16 PKl[16 * 128];
  __shared__ bf16 PVl[128 * 16];
  __shared__ bf16 Pl[4][16 * 64];
  const int tid = threadIdx.x, w = tid >> 6, l = tid & 63;
  const int lg = l >> 4, lr = l & 15;
  const int qb = blockIdx.x, bh = blockIdx.y;
  const int b = bh >> 5, h = bh & 31;
  const int q0 = qb * 64 + w * 16;

  short8 qf[4];
  {
    const bf16* qp = Q + ((long)(b * 1024 + q0 + lr)) * 4096 + h * 128 + lg * 8;
    const int s = q0 + lr;
#pragma unroll
    for (int c = 0; c < 4; c++) {
      short8 v = *(const short8*)(qp + c * 32);
      f32x4 fc = *(const f32x4*)(FC + s * 64 + c * 16 + lg * 4);
      f32x4 fs = *(const f32x4*)(FS + s * 64 + c * 16 + lg * 4);
#pragma unroll
      for (int j = 0; j < 4; j++) {
        float e = bf2f(v[2 * j]), od = bf2f(v[2 * j + 1]);
        v[2 * j] = f2bf(e * fc[j] - od * fs[j]);
        v[2 * j + 1] = f2bf(e * fs[j] + od * fc[j]);
      }
      qf[c] = v;
    }
  }
  {
    int rowp = tid >> 4, pc = tid & 15, lc = pc ^ (rowp & 7);
    short8 v = {0, 0, 0, 0, 0, 0, 0, 0};
    if (rowp < 10) v = *(const short8*)(PK + (long)rowp * 4096 + h * 128 + lc * 8);
    *(short8*)((char*)PKl + tid * 16) = v;
  }
  {
    int d = tid >> 1, pb = (tid & 1) * 8;
#pragma unroll
    for (int e = 0; e < 8; e++) {
      int p = pb + e;
      short v = 0;
      if (p < 10) v = __builtin_bit_cast(short, PV[(long)p * 4096 + h * 128 + d]);
      *(short*)((char*)PVl + d * 32 + (((p >> 3) ^ (d & 1)) * 16) + (p & 7) * 2) = v;
    }
  }
  const float gate = GATE[h];

  f32x4 o[8];
#pragma unroll
  for (int i = 0; i < 8; i++) o[i] = (f32x4){0.f, 0.f, 0.f, 0.f};
  float m_[4] = {-1e30f, -1e30f, -1e30f, -1e30f};
  float l_[4] = {0.f, 0.f, 0.f, 0.f};

  const int nt = qb + 1;   // 64-key tiles
  const bf16* Kbase = Kg + ((long)b * 1024) * 4096 + h * 128;
  const bf16* Vbase = VT + ((long)bh) * 128 * 1024;
  bf16* pw = &Pl[w][0];

#define FSTG(BUF_, J_)                                                        \
  {                                                                           \
    _Pragma("unroll") for (int r_ = 0; r_ < 4; ++r_) {                        \
      int i_ = tid + 256 * r_;                                                \
      int kr_ = i_ >> 4, kc_ = (i_ & 15) ^ (kr_ & 7);                         \
      gl_lds16(Kbase + (long)((J_) * 64 + kr_) * 4096 + kc_ * 8,              \
               &Kl[BUF_][0] + i_ * 8);                                        \
      int vd_ = i_ >> 3, vc_ = (i_ & 7) ^ (vd_ & 7);                          \
      gl_lds16(Vbase + (long)vd_ * 1024 + (J_) * 64 + vc_ * 8,                \
               &Vl[BUF_][0] + i_ * 8);                                        \
    }                                                                         \
  }

  FSTG(0, 0)
  for (int j = 0; j < nt; ++j) {
    __builtin_amdgcn_s_barrier();
    if (j + 1 < nt) {
      FSTG((j + 1) & 1, j + 1)
      asm volatile("s_waitcnt vmcnt(8)" ::: "memory");
    } else {
      asm volatile("s_waitcnt vmcnt(0)" ::: "memory");
    }
    __builtin_amdgcn_s_barrier();
    __builtin_amdgcn_sched_barrier(0);

    const char* kb = (const char*)&Kl[j & 1][0];
    const char* vb = (const char*)&Vl[j & 1][0];

    f32x4 s[4];
#pragma unroll
    for (int ns = 0; ns < 4; ns++) {
      f32x4 a = (f32x4){0.f, 0.f, 0.f, 0.f};
      int krow = ns * 16 + lr;
      int sw = krow & 7;
#pragma unroll
      for (int c = 0; c < 4; c++) {
        short8 kf = *(const short8*)(kb + krow * 256 + (((c * 4 + lg) ^ sw) * 16));
        a = mfma16(qf[c], kf, a);
      }
      int key = j * 64 + krow;
#pragma unroll
      for (int r = 0; r < 4; r++) {
        int qr = q0 + lg * 4 + r;
        s[ns][r] = a[r] * SCALE_ + ((key <= qr) ? 0.0f : -1e30f);
      }
    }
    // online softmax over 64 keys (always-rescale, round-10 verified)
    float mx[4], cor[4], sum[4];
#pragma unroll
    for (int r = 0; r < 4; r++)
      mx[r] = fmaxf(fmaxf(s[0][r], s[1][r]), fmaxf(s[2][r], s[3][r]));
#pragma unroll
    for (int xm = 1; xm < 16; xm <<= 1)
#pragma unroll
      for (int r = 0; r < 4; r++) mx[r] = fmaxf(mx[r], __shfl_xor(mx[r], xm, 64));
#pragma unroll
    for (int r = 0; r < 4; r++) {
      float mn = fmaxf(m_[r], mx[r]);
      cor[r] = __expf(m_[r] - mn);
      m_[r] = mn;
      sum[r] = 0.f;
    }
#pragma unroll
    for (int ns = 0; ns < 4; ns++)
#pragma unroll
      for (int r = 0; r < 4; r++) {
        s[ns][r] = __expf(s[ns][r] - m_[r]);
        sum[r] += s[ns][r];
      }
#pragma unroll
    for (int xm = 1; xm < 16; xm <<= 1)
#pragma unroll
      for (int r = 0; r < 4; r++) sum[r] += __shfl_xor(sum[r], xm, 64);
#pragma unroll
    for (int r = 0; r < 4; r++) l_[r] = l_[r] * cor[r] + sum[r];
#pragma unroll
    for (int df = 0; df < 8; df++)
#pragma unroll
      for (int r = 0; r < 4; r++) o[df][r] *= cor[r];

    // P (C-layout) -> per-wave swizzled LDS -> A-frags
#pragma unroll
    for (int ns = 0; ns < 4; ns++)
#pragma unroll
      for (int r = 0; r < 4; r++) {
        int row = lg * 4 + r;
        int ch = ns * 2 + (lr >> 3);
        *(short*)((char*)pw + row * 128 + ((ch ^ (row & 7)) * 16) + (lr & 7) * 2)
            = f2bf(s[ns][r]);
      }
    asm volatile("s_waitcnt lgkmcnt(0)" ::: "memory");
    __builtin_amdgcn_sched_barrier(0);
    short8 pf0 = *(const short8*)((char*)pw + lr * 128 + ((lg ^ (lr & 7)) * 16));
    short8 pf1 = *(const short8*)((char*)pw + lr * 128 + (((4 + lg) ^ (lr & 7)) * 16));

#pragma unroll
    for (int df = 0; df < 8; df++) {
      int d = df * 16 + lr;
      short8 vf0 = *(const short8*)(vb + d * 128 + ((lg ^ (d & 7)) * 16));
      short8 vf1 = *(const short8*)(vb + d * 128 + (((4 + lg) ^ (d & 7)) * 16));
      o[df] = mfma16(pf0, vf0, o[df]);
      o[df] = mfma16(pf1, vf1, o[df]);
    }
  }
#undef FSTG

  // ---- prompt attention (separate softmax, gated) ----
  f32x4 ps;
  {
    f32x4 a = (f32x4){0.f, 0.f, 0.f, 0.f};
    const char* kp = (const char*)PKl + lr * 256;
    int sw = lr & 7;
#pragma unroll
    for (int c = 0; c < 4; c++) {
      short8 kf = *(const short8*)(kp + (((c * 4 + lg) ^ sw) * 16));
      a = mfma16(qf[c], kf, a);
    }
#pragma unroll
    for (int r = 0; r < 4; r++) ps[r] = (lr < 10) ? a[r] * SCALE_ : -1e30f;
  }
  {
    float pm[4], pss[4];
#pragma unroll
    for (int r = 0; r < 4; r++) pm[r] = ps[r];
#pragma unroll
    for (int xm = 1; xm < 16; xm <<= 1)
#pragma unroll
      for (int r = 0; r < 4; r++) pm[r] = fmaxf(pm[r], __shfl_xor(pm[r], xm, 64));
#pragma unroll
    for (int r = 0; r < 4; r++) { ps[r] = __expf(ps[r] - pm[r]); pss[r] = ps[r]; }
#pragma unroll
    for (int xm = 1; xm < 16; xm <<= 1)
#pragma unroll
      for (int r = 0; r < 4; r++) pss[r] += __shfl_xor(pss[r], xm, 64);
#pragma unroll
    for (int r = 0; r < 4; r++) ps[r] = ps[r] / pss[r];
  }
#pragma unroll
  for (int r = 0; r < 4; r++) {
    int row = lg * 4 + r;
    int ch0 = (lr >> 3);
    *(short*)((char*)pw + row * 128 + ((ch0 ^ (row & 7)) * 16) + (lr & 7) * 2) = f2bf(ps[r]);
    int ch1 = 2 + (lr >> 3);
    *(short*)((char*)pw + row * 128 + ((ch1 ^ (row & 7)) * 16) + (lr & 7) * 2) = 0;
  }
  asm volatile("s_waitcnt lgkmcnt(0)" ::: "memory");
  __builtin_amdgcn_sched_barrier(0);
  short8 pf2 = *(const short8*)((char*)pw + lr * 128 + ((lg ^ (lr & 7)) * 16));
  f32x4 po[8];
#pragma unroll
  for (int df = 0; df < 8; df++) {
    int d = df * 16 + lr;
    short8 vf = {0, 0, 0, 0, 0, 0, 0, 0};
    if (lg < 2) vf = *(const short8*)((const char*)PVl + d * 32 + ((lg ^ (d & 1)) * 16));
    po[df] = mfma16(pf2, vf, (f32x4){0.f, 0.f, 0.f, 0.f});
  }

  bf16* op = O + ((long)(b * 1024 + q0 + lg * 4)) * 4096 + h * 128 + lr;
#pragma unroll
  for (int df = 0; df < 8; df++)
#pragma unroll
    for (int r = 0; r < 4; r++) {
      float val = o[df][r] / l_[r] + gate * po[df][r];
      *(short*)(op + (long)r * 4096 + df * 16) = f2bf(val);
    }
}

// ---------------------------------------------------------------------------
extern "C" void kernel_launch(void* const* d_in, const int* in_sizes, int n_in,
                              void* d_out, int out_size, void* d_ws, size_t ws_size,
                              hipStream_t stream) {
  (void)in_sizes; (void)n_in; (void)out_size; (void)ws_size;
  const float* x      = (const float*)d_in[0];
  const float* wq     = (const float*)d_in[1];
  const float* wk     = (const float*)d_in[2];
  const float* wv     = (const float*)d_in[3];
  const float* wo     = (const float*)d_in[4];
  const float* prompt = (const float*)d_in[5];
  const float* gate   = (const float*)d_in[6];
  const float* fcos   = (const float*)d_in[7];
  const float* fsin   = (const float*)d_in[8];
  float* out = (float*)d_out;
  char* ws = (char*)d_ws;

  size_t o = 0;
  bf16* xb  = (bf16*)(ws + o); o += (size_t)8388608 * 2;
  bf16* wqb = (bf16*)(ws + o); o += (size_t)16777216 * 2;
  bf16* wkb = (bf16*)(ws + o); o += (size_t)16777216 * 2;
  bf16* wvb = (bf16*)(ws + o); o += (size_t)16777216 * 2;
  bf16* wob = (bf16*)(ws + o); o += (size_t)16777216 * 2;
  bf16* pb  = (bf16*)(ws + o); o += (size_t)40960 * 2;
  bf16* q_ws  = (bf16*)(ws + o); o += (size_t)2048 * 4096 * 2;
  bf16* k_ws  = (bf16*)(ws + o); o += (size_t)2048 * 4096 * 2;
  bf16* v_ws  = (bf16*)(ws + o); o += (size_t)2048 * 4096 * 2;
  bf16* vT_ws = (bf16*)(ws + o); o += (size_t)2048 * 4096 * 2;
  bf16* pk_ws = (bf16*)(ws + o); o += (size_t)40960 * 2;
  bf16* pv_ws = (bf16*)(ws + o); o += (size_t)40960 * 2;
  bf16* attn_ws = v_ws;

  // 1. downcast inputs to bf16
  cvt6<<<dim3(36884), 256, 0, stream>>>(x, wq, wk, wv, wo, prompt,
                                        xb, wqb, wkb, wvb, wob, pb);
  // 2. QKV (+prompt K/V rows): 9 m-tiles x 16 n-tiles per z
  gemm_bt<64, false><<<dim3(144, 1, 3), 512, 0, stream>>>(
      xb, pb, wqb, wkb, wvb, q_ws, k_ws, v_ws, pk_ws, pv_ws, (float*)0, 2048, 2058);
  // 3. K-RoPE + V->VT (Q-RoPE fused into flash)
  prep_qkv<<<dim3(2048, 2), 256, 0, stream>>>(k_ws, fcos, fsin, v_ws, vT_ws);
  // 4. flash attention v3b (Q-rope fused, always-rescale softmax)
  flash_attn<<<dim3(16, 64), 256, 0, stream>>>(
      q_ws, k_ws, vT_ws, pk_ws, pv_ws, gate, fcos, fsin, attn_ws);
  // 5. output projection: 256x128 tiles, 256 blocks, f32 out
  gemm_n128<<<dim3(256), 512, 0, stream>>>(attn_ws, wob, out);
}